// Round 1
// 1526.055 us; speedup vs baseline: 1.0163x; 1.0163x over previous
//
#include <hip/hip_runtime.h>
#include <math.h>

#define MASKN 1023

typedef unsigned short ushort_t;
typedef __attribute__((ext_vector_type(8))) short short8;
typedef __attribute__((ext_vector_type(4))) float floatx4;
typedef __attribute__((ext_vector_type(4))) unsigned short us4v;   // 8B-aligned bf16x4

// tanh-form GELU as x * sigmoid(2*0.7978845608*(x + 0.044715 x^3)); one v_exp_f32.
// max |diff| vs exact erf-gelu ~3e-4, far under the bf16 noise already present.
__device__ __forceinline__ float gelu_f(float x) {
    float x2 = x * x;
    float inner = fmaf(0.044715f * x, x2, x);
    float t = exp2f(inner * -2.302089214f);   // 2^(-2*0.7978845608*log2(e)*inner)
    return x / (1.0f + t);
}

// ---- bf16 storage helpers (compute stays fp32) ----
__device__ __forceinline__ float bf2f(ushort_t h) {
    return __uint_as_float(((unsigned int)h) << 16);
}
__device__ __forceinline__ ushort_t f2bf(float f) {
    unsigned int u = __float_as_uint(f);
    u += 0x7FFFu + ((u >> 16) & 1u);   // round to nearest even
    return (ushort_t)(u >> 16);
}
struct us4 { ushort_t x, y, z, w; };

__device__ __forceinline__ void st4(ushort_t* p, float4 v) {
    us4 h; h.x = f2bf(v.x); h.y = f2bf(v.y); h.z = f2bf(v.z); h.w = f2bf(v.w);
    *(us4*)p = h;
}

// ---------------- twiddle step table for k_f2 / k_i1
__global__ void k_fill_tw(float* __restrict__ ct, float* __restrict__ st) {
    int j = blockIdx.x * 256 + threadIdx.x;   // 0..1023
    float ang = (float)j * (6.283185307179586f / 1024.0f);
    float s, c;
    sincosf(ang, &s, &c);
    ct[j] = c; st[j] = s;
}

// ---------------- T1 table: T1[k2p][y], [2k2][y]=cos(2pi k2 y/1024), [2k2+1][y]=-sin, hi/lo split
__global__ void k_fill_T1(ushort_t* __restrict__ T1h, ushort_t* __restrict__ T1l) {
    int idx = blockIdx.x * 256 + threadIdx.x;   // 0..65535
    int k2p = idx >> 10, y = idx & 1023;
    int k2 = k2p >> 1;
    float ang = (float)((k2 * y) & MASKN) * (6.283185307179586f / 1024.0f);
    float s, c;
    sincosf(ang, &s, &c);
    float v = (k2p & 1) ? -s : c;
    ushort_t h = f2bf(v);
    T1h[idx] = h;
    T1l[idx] = f2bf(v - bf2f(h));
}

// ---------------- T2 table: T2[n2][kk], [n2][2k2]=cos(2pi n2 k2/1024), [n2][2k2+1]=-sin, hi/lo
__global__ void k_fill_T2(ushort_t* __restrict__ T2h, ushort_t* __restrict__ T2l) {
    int idx = blockIdx.x * 256 + threadIdx.x;   // 0..65535
    int n2 = idx >> 6, kk = idx & 63;
    int k2 = kk >> 1;
    float ang = (float)((k2 * n2) & MASKN) * (6.283185307179586f / 1024.0f);
    float s, c;
    sincosf(ang, &s, &c);
    float v = (kk & 1) ? -s : c;
    ushort_t h = f2bf(v);
    T2h[idx] = h;
    T2l[idx] = f2bf(v - bf2f(h));
}

// ---------------- wT tables: wT[l][d][c] = w_l[c][d], hi/lo
__global__ void k_fill_wT(const float* __restrict__ w1, const float* __restrict__ w2,
        const float* __restrict__ w3, const float* __restrict__ w4,
        ushort_t* __restrict__ wTh, ushort_t* __restrict__ wTl) {
    int l = blockIdx.y;
    int i = blockIdx.x * 256 + threadIdx.x;   // 0..4095
    int d = i >> 6, c = i & 63;
    const float* w = (l == 0) ? w1 : (l == 1) ? w2 : (l == 2) ? w3 : w4;
    float v = w[c * 64 + d];
    ushort_t h = f2bf(v);
    wTh[l * 4096 + i] = h;
    wTl[l * 4096 + i] = f2bf(v - bf2f(h));
}

// ---------------- shallow: vt[p][c] = gelu(in[p][0]*Wsh[0][c] + in[p][1]*Wsh[1][c] + bsh[c])
__global__ __launch_bounds__(256) void k_shallow(const float* __restrict__ in,
        const float* __restrict__ Wsh, const float* __restrict__ bsh,
        ushort_t* __restrict__ vt) {
    int tid = blockIdx.x * 256 + threadIdx.x;
    int p = tid >> 4, c0 = (tid & 15) << 2;
    float a0 = in[p * 2], a1 = in[p * 2 + 1];
    float4 w0 = *(const float4*)&Wsh[c0];
    float4 w1 = *(const float4*)&Wsh[64 + c0];
    float4 b  = *(const float4*)&bsh[c0];
    float4 r;
    r.x = gelu_f(fmaf(a0, w0.x, fmaf(a1, w1.x, b.x)));
    r.y = gelu_f(fmaf(a0, w0.y, fmaf(a1, w1.y, b.y)));
    r.z = gelu_f(fmaf(a0, w0.z, fmaf(a1, w1.z, b.z)));
    r.w = gelu_f(fmaf(a0, w0.w, fmaf(a1, w1.w, b.w)));
    st4(&vt[(size_t)p * 64 + c0], r);
}

// ---------------- F1 (MFMA): gT[x][c][k2p] = sum_y vt[x][y][c] * T1[k2p][y]
// block = one x; double-buffered LDS transpose, register prefetch of next chunk,
// single barrier per chunk.
#define F1S 136   // LDS row stride (bf16) for transposed vt tile
__global__ __launch_bounds__(256) void k_f1(const ushort_t* __restrict__ vt,
        const ushort_t* __restrict__ T1h, const ushort_t* __restrict__ T1l,
        float* __restrict__ gT) {
    __shared__ __align__(16) ushort_t vs[2][64 * F1S];   // 2 x 17408 B
    int t = threadIdx.x;
    int x = blockIdx.x;
    int wv = t >> 6, ln = t & 63;
    int lm = ln & 15, quad = ln >> 4;
    int mt = wv;                          // wave's m-tile (16 c rows)
    int lrow = t & 127, chalf = (t >> 7) * 32;   // staging map
    floatx4 acc[4];
    #pragma unroll
    for (int nt = 0; nt < 4; ++nt) acc[nt] = (floatx4)(0.f);
    const ushort_t* vrow = vt + (size_t)x * 65536;
    uint4 pf[4];
    {
        const ushort_t* src = vrow + (size_t)lrow * 64 + chalf;
        #pragma unroll
        for (int i = 0; i < 4; ++i) pf[i] = *(const uint4*)(src + i * 8);
    }
    for (int ch = 0; ch < 8; ++ch) {
        ushort_t* vsb = vs[ch & 1];
        // scatter staged registers transposed into LDS: vs[c][y]
        #pragma unroll
        for (int i = 0; i < 4; ++i) {
            union { uint4 u; ushort_t e[8]; } uv;
            uv.u = pf[i];
            #pragma unroll
            for (int j = 0; j < 8; ++j)
                vsb[(chalf + i * 8 + j) * F1S + lrow] = uv.e[j];
        }
        // prefetch next chunk (overlaps barrier + MFMA below)
        if (ch < 7) {
            const ushort_t* src = vrow + (size_t)((ch + 1) * 128 + lrow) * 64 + chalf;
            #pragma unroll
            for (int i = 0; i < 4; ++i) pf[i] = *(const uint4*)(src + i * 8);
        }
        __syncthreads();
        #pragma unroll
        for (int ks = 0; ks < 4; ++ks) {
            short8 af = *(const short8*)&vsb[(mt * 16 + lm) * F1S + ks * 32 + quad * 8];
            int ybase = ch * 128 + ks * 32 + quad * 8;
            #pragma unroll
            for (int nt = 0; nt < 4; ++nt) {
                short8 bh = *(const short8*)(T1h + (size_t)(nt * 16 + lm) * 1024 + ybase);
                short8 bl = *(const short8*)(T1l + (size_t)(nt * 16 + lm) * 1024 + ybase);
                acc[nt] = __builtin_amdgcn_mfma_f32_16x16x32_bf16(af, bh, acc[nt], 0, 0, 0);
                acc[nt] = __builtin_amdgcn_mfma_f32_16x16x32_bf16(af, bl, acc[nt], 0, 0, 0);
            }
        }
    }
    float* grow = gT + (size_t)x * 4096;
    #pragma unroll
    for (int nt = 0; nt < 4; ++nt)
        #pragma unroll
        for (int r = 0; r < 4; ++r)
            grow[(mt * 16 + quad * 4 + r) * 64 + nt * 16 + lm] = acc[nt][r];
}

// ---------------- F2: fp[cx][k1*32+k2][c] = sum_{x in cx} g[x][k2][c] (x) e^{-2pi i k1 x/1024}
// grid (8 cx, 16 cg, 4 k1-groups)
__global__ __launch_bounds__(256) void k_f2(const float* __restrict__ gT,
        const float* __restrict__ ct, const float* __restrict__ st,
        float* __restrict__ fpr, float* __restrict__ fpi) {
    int t = threadIdx.x;
    int cx = blockIdx.x;          // 0..7
    int cg = blockIdx.y;          // 0..15
    int k10 = blockIdx.z * 8;     // 0,8,16,24
    int l = t & 63;               // k2p
    int q = t >> 6;               // 0..3
    int c = cg * 4 + q;
    int e = l & 1;                // 0 = re lane, 1 = im lane
    int k2 = l >> 1;
    float acc[8];
    #pragma unroll
    for (int i = 0; i < 8; ++i) acc[i] = 0.f;
    for (int xi = 0; xi < 128; ++xi) {
        int x = cx * 128 + xi;
        float v = gT[(size_t)x * 4096 + c * 64 + l];
        float p = __shfl_xor(v, 1);
        float gr = e ? p : v;
        float gi = e ? v : p;
        float u  = e ? gi : gr;
        float w2 = e ? -gr : gi;
        float cb = ct[x], sb = st[x];
        int ph = (x * k10) & MASKN;
        float cr = ct[ph], sr = st[ph];
        #pragma unroll
        for (int j = 0; j < 8; ++j) {
            acc[j] = fmaf(u, cr, fmaf(w2, sr, acc[j]));
            float nc = fmaf(cr, cb, -sr * sb);
            float ns = fmaf(sr, cb, cr * sb);
            cr = nc; sr = ns;
        }
    }
    float* dst = e ? fpi : fpr;
    #pragma unroll
    for (int j = 0; j < 8; ++j)
        dst[(size_t)cx * 65536 + ((k10 + j) * 32 + k2) * 64 + c] = acc[j];
}

// ---------------- MIX: Rf[m,d] = sum_c f[m,c] * (Rr+iRi)[m,c,d], f = sum of 8 partials
__global__ __launch_bounds__(64) void k_mix(const float* __restrict__ fpr, const float* __restrict__ fpi,
        const float* __restrict__ Rr, const float* __restrict__ Ri,
        float* __restrict__ Rfr, float* __restrict__ Rfi) {
    __shared__ float fr[64], fi[64];
    int m = blockIdx.x;
    int d = threadIdx.x;
    float sr = 0.f, si = 0.f;
    #pragma unroll
    for (int ch = 0; ch < 8; ++ch) {
        sr += fpr[(size_t)ch * 65536 + m * 64 + d];
        si += fpi[(size_t)ch * 65536 + m * 64 + d];
    }
    fr[d] = sr; fi[d] = si;
    __syncthreads();
    const float* Rrb = Rr + (size_t)m * 4096;
    const float* Rib = Ri + (size_t)m * 4096;
    float ar = 0.f, ai = 0.f;
    for (int c = 0; c < 64; ++c) {
        float rr = Rrb[c * 64 + d], ri = Rib[c * 64 + d];
        ar = fmaf(fr[c], rr, fmaf(-fi[c], ri, ar));
        ai = fmaf(fr[c], ri, fmaf(fi[c], rr, ai));
    }
    Rfr[m * 64 + d] = ar;
    Rfi[m * 64 + d] = ai;
}

// ---------------- I1: Bmat[n1][d][kk] (bf16 hi/lo, kk = 2k2(+1) = re/im interleaved)
__global__ __launch_bounds__(256) void k_i1(const float* __restrict__ Rfr, const float* __restrict__ Rfi,
        const float* __restrict__ ctg, const float* __restrict__ stg,
        ushort_t* __restrict__ Bh, ushort_t* __restrict__ Bl) {
    __shared__ float ct[1024], st[1024];
    int t = threadIdx.x;
    #pragma unroll
    for (int i = 0; i < 4; ++i) { int j = t + 256 * i; ct[j] = ctg[j]; st[j] = stg[j]; }
    __syncthreads();
    int n1 = blockIdx.x;
    int d = t & 63;
    int k20 = (t >> 6) * 8;
    float br[8], bi[8];
    #pragma unroll
    for (int j = 0; j < 8; ++j) { br[j] = 0.f; bi[j] = 0.f; }
    int idx = 0;
    for (int k1 = 0; k1 < 32; ++k1) {
        float cc = ct[idx], ss = st[idx];
        idx = (idx + n1) & MASKN;
        #pragma unroll
        for (int j = 0; j < 8; ++j) {
            float rr = Rfr[(k1 * 32 + k20 + j) * 64 + d];
            float ri = Rfi[(k1 * 32 + k20 + j) * 64 + d];
            br[j] = fmaf(rr, cc, fmaf(-ri, ss, br[j]));
            bi[j] = fmaf(rr, ss, fmaf(ri, cc, bi[j]));
        }
    }
    union { uint4 u[2]; ushort_t e[16]; } hh, ll;
    #pragma unroll
    for (int j = 0; j < 8; ++j) {
        int k2 = k20 + j;
        float sc = (k2 == 0 ? 1.0f : 2.0f) * 9.5367431640625e-7f;   // 1/2^20
        float vr = br[j] * sc, vi = bi[j] * sc;
        ushort_t hr = f2bf(vr), hi2 = f2bf(vi);
        hh.e[2 * j] = hr;          hh.e[2 * j + 1] = hi2;
        ll.e[2 * j] = f2bf(vr - bf2f(hr));
        ll.e[2 * j + 1] = f2bf(vi - bf2f(hi2));
    }
    size_t base = ((size_t)n1 * 64 + d) * 64 + 2 * k20;
    *(uint4*)(Bh + base) = hh.u[0];
    *(uint4*)(Bh + base + 8) = hh.u[1];
    *(uint4*)(Bl + base) = ll.u[0];
    *(uint4*)(Bl + base + 8) = ll.u[1];
}

// ---------------- I2 (MFMA, fused skip+inverse): vt[n1][n2][d] = gelu( T2[n2,:]@Bmat[n1][:, d] + vt[n1][n2,:]@w[:,d] )
// OPERANDS SWAPPED vs previous version: A-side = Bmat/wT (rows = d), B-side = T2/vt
// (rows = n2).  C-layout (row = quad*4+r, col = lm) then gives each thread 4
// CONTIGUOUS d per fragment -> epilogue is 8x 8-byte stores instead of 32x 2-byte.
// __launch_bounds__(256,4): cap VGPR at 128 (was compiler-capped to 64 -> no load
// pipelining, fully latency-bound: MfmaUtil 9.6%, HBM 18%).
// grid (8 n2-chunks, 1024 n1); 4 waves; wave = 32 n2 x 64 d; no LDS, no barriers.
// FINAL=true: fuse the output projection (out = gelu(.)@Wp + bp), skip the vt store.
template<bool FINAL>
__global__ __launch_bounds__(256, 4) void k_i2(ushort_t* __restrict__ vt,
        const ushort_t* __restrict__ Bh, const ushort_t* __restrict__ Bl,
        const ushort_t* __restrict__ T2h, const ushort_t* __restrict__ T2l,
        const ushort_t* __restrict__ wTh, const ushort_t* __restrict__ wTl,
        const float* __restrict__ Wp, const float* __restrict__ bp,
        float* __restrict__ out) {
    int t = threadIdx.x;
    int wv = t >> 6, ln = t & 63;
    int lm = ln & 15, quad = ln >> 4;
    int chunk = blockIdx.x, n1 = blockIdx.y;
    int n2b = chunk * 128 + wv * 32;
    const ushort_t* Bhr = Bh + (size_t)n1 * 4096;
    const ushort_t* Blr = Bl + (size_t)n1 * 4096;
    ushort_t* vrow = vt + ((size_t)n1 * 1024 + n2b) * 64;

    // hoist the HBM loads (skip-connection vt) to the very top: their latency
    // overlaps all of phase 1.
    short8 v[2][2];
    #pragma unroll
    for (int ks = 0; ks < 2; ++ks)
        #pragma unroll
        for (int nt = 0; nt < 2; ++nt)
            v[ks][nt] = *(const short8*)(vrow + (size_t)(nt * 16 + lm) * 64 + ks * 32 + quad * 8);

    floatx4 acc[4][2];   // [d-tile][n2-tile]
    #pragma unroll
    for (int mt = 0; mt < 4; ++mt)
        #pragma unroll
        for (int nt = 0; nt < 2; ++nt) acc[mt][nt] = (floatx4)(0.f);

    // phase 1: Bmat (A, rows=d, hi/lo) x T2 (B, rows=n2, hi/lo): hh + lh + hl
    #pragma unroll
    for (int ks = 0; ks < 2; ++ks) {
        int kk = ks * 32 + quad * 8;
        short8 th[2], tl[2];
        #pragma unroll
        for (int nt = 0; nt < 2; ++nt) {
            th[nt] = *(const short8*)(T2h + (size_t)(n2b + nt * 16 + lm) * 64 + kk);
            tl[nt] = *(const short8*)(T2l + (size_t)(n2b + nt * 16 + lm) * 64 + kk);
        }
        #pragma unroll
        for (int mt = 0; mt < 4; ++mt) {
            short8 ah = *(const short8*)(Bhr + (size_t)(mt * 16 + lm) * 64 + kk);
            short8 al = *(const short8*)(Blr + (size_t)(mt * 16 + lm) * 64 + kk);
            #pragma unroll
            for (int nt = 0; nt < 2; ++nt) {
                acc[mt][nt] = __builtin_amdgcn_mfma_f32_16x16x32_bf16(ah, th[nt], acc[mt][nt], 0, 0, 0);
                acc[mt][nt] = __builtin_amdgcn_mfma_f32_16x16x32_bf16(al, th[nt], acc[mt][nt], 0, 0, 0);
                acc[mt][nt] = __builtin_amdgcn_mfma_f32_16x16x32_bf16(ah, tl[nt], acc[mt][nt], 0, 0, 0);
            }
        }
    }
    // phase 2: wT (A, rows=d, hi/lo) x vt (B, rows=n2)
    #pragma unroll
    for (int ks = 0; ks < 2; ++ks) {
        int cc = ks * 32 + quad * 8;
        #pragma unroll
        for (int mt = 0; mt < 4; ++mt) {
            short8 wh = *(const short8*)(wTh + (mt * 16 + lm) * 64 + cc);
            short8 wl = *(const short8*)(wTl + (mt * 16 + lm) * 64 + cc);
            #pragma unroll
            for (int nt = 0; nt < 2; ++nt) {
                acc[mt][nt] = __builtin_amdgcn_mfma_f32_16x16x32_bf16(wh, v[ks][nt], acc[mt][nt], 0, 0, 0);
                acc[mt][nt] = __builtin_amdgcn_mfma_f32_16x16x32_bf16(wl, v[ks][nt], acc[mt][nt], 0, 0, 0);
            }
        }
    }
    if (!FINAL) {
        // epilogue: gelu + bf16; thread owns d = mt*16 + quad*4 + r (contiguous r)
        // at n2 = n2b + nt*16 + lm  ->  8x 8-byte stores.
        #pragma unroll
        for (int nt = 0; nt < 2; ++nt) {
            size_t rowoff = (size_t)(nt * 16 + lm) * 64;
            #pragma unroll
            for (int mt = 0; mt < 4; ++mt) {
                us4v h;
                h.x = f2bf(gelu_f(acc[mt][nt][0]));
                h.y = f2bf(gelu_f(acc[mt][nt][1]));
                h.z = f2bf(gelu_f(acc[mt][nt][2]));
                h.w = f2bf(gelu_f(acc[mt][nt][3]));
                *(us4v*)(vrow + rowoff + mt * 16 + quad * 4) = h;
            }
        }
    } else {
        // fused projection: out[n1][n2] = sum_d gelu(acc) * Wp[d] + bp.
        // thread holds 16 d-values per nt; reduce the 4 quads with shfl_xor.
        float bp0 = bp[0];
        #pragma unroll
        for (int nt = 0; nt < 2; ++nt) {
            float s = 0.f;
            #pragma unroll
            for (int mt = 0; mt < 4; ++mt) {
                float4 wp = *(const float4*)&Wp[mt * 16 + quad * 4];
                s = fmaf(gelu_f(acc[mt][nt][0]), wp.x, s);
                s = fmaf(gelu_f(acc[mt][nt][1]), wp.y, s);
                s = fmaf(gelu_f(acc[mt][nt][2]), wp.z, s);
                s = fmaf(gelu_f(acc[mt][nt][3]), wp.w, s);
            }
            s += __shfl_xor(s, 16);
            s += __shfl_xor(s, 32);
            if (quad == 0)
                out[(size_t)n1 * 1024 + n2b + nt * 16 + lm] = s + bp0;
        }
    }
}

extern "C" void kernel_launch(void* const* d_in, const int* in_sizes, int n_in,
                              void* d_out, int out_size, void* d_ws, size_t ws_size,
                              hipStream_t stream) {
    const float* in  = (const float*)d_in[0];
    const float* Wsh = (const float*)d_in[1];
    const float* bsh = (const float*)d_in[2];
    const float* Wp  = (const float*)d_in[15];
    const float* bp  = (const float*)d_in[16];

    // workspace layout (~151.9 MB, proven to fit)
    char* wsb = (char*)d_ws;
    ushort_t* vt   = (ushort_t*)wsb;                          // 1024*1024*64 bf16 = 134,217,728 B
    float* ctab = (float*)(wsb + 134217728);                  // 1024
    float* stab = ctab + 1024;                                // 1024
    float* gT   = stab + 1024;                                // 1024*64*64 f32 = 16 MB
    float* Rfr  = gT + 4194304;                               // 65536
    float* Rfi  = Rfr + 65536;                                // 65536
    ushort_t* T1h = (ushort_t*)(Rfi + 65536);                 // 64*1024
    ushort_t* T1l = T1h + 65536;
    ushort_t* T2h = T1l + 65536;                              // 1024*64
    ushort_t* T2l = T2h + 65536;
    ushort_t* wTh = T2l + 65536;                              // 4*64*64
    ushort_t* wTl = wTh + 16384;
    ushort_t* Bh  = (ushort_t*)gT;                            // alias gT (dead after k_f2)
    ushort_t* Bl  = Bh + 4194304;
    float* fpr = (float*)d_out;                               // alias d_out (dead before final k_i2)
    float* fpi = fpr + 524288;

    k_fill_tw<<<4, 256, 0, stream>>>(ctab, stab);
    k_fill_T1<<<256, 256, 0, stream>>>(T1h, T1l);
    k_fill_T2<<<256, 256, 0, stream>>>(T2h, T2l);
    k_fill_wT<<<dim3(16, 4), 256, 0, stream>>>((const float*)d_in[5], (const float*)d_in[8],
                                               (const float*)d_in[11], (const float*)d_in[14], wTh, wTl);
    k_shallow<<<65536, 256, 0, stream>>>(in, Wsh, bsh, vt);
    for (int L = 0; L < 4; ++L) {
        const float* Rr = (const float*)d_in[3 + L * 3];
        const float* Ri = (const float*)d_in[4 + L * 3];
        k_f1<<<1024, 256, 0, stream>>>(vt, T1h, T1l, gT);
        k_f2<<<dim3(8, 16, 4), 256, 0, stream>>>(gT, ctab, stab, fpr, fpi);
        k_mix<<<1024, 64, 0, stream>>>(fpr, fpi, Rr, Ri, Rfr, Rfi);
        k_i1<<<1024, 256, 0, stream>>>(Rfr, Rfi, ctab, stab, Bh, Bl);
        if (L < 3) {
            k_i2<false><<<dim3(8, 1024), 256, 0, stream>>>(vt, Bh, Bl, T2h, T2l,
                    wTh + L * 4096, wTl + L * 4096, nullptr, nullptr, nullptr);
        } else {
            // final layer: fuse projection, write d_out directly (fp partials in
            // d_out are dead after k_mix); vt is never stored again.
            k_i2<true><<<dim3(8, 1024), 256, 0, stream>>>(vt, Bh, Bl, T2h, T2l,
                    wTh + L * 4096, wTl + L * 4096, Wp, bp, (float*)d_out);
        }
    }
}

// Round 2
// 1525.638 us; speedup vs baseline: 1.0166x; 1.0003x over previous
//
#include <hip/hip_runtime.h>
#include <math.h>

#define MASKN 1023

typedef unsigned short ushort_t;
typedef __attribute__((ext_vector_type(8))) short short8;
typedef __attribute__((ext_vector_type(4))) float floatx4;
typedef __attribute__((ext_vector_type(4))) unsigned short us4v;   // 8B-aligned bf16x4

// tanh-form GELU as x * sigmoid(2*0.7978845608*(x + 0.044715 x^3)); one v_exp_f32.
// max |diff| vs exact erf-gelu ~3e-4, far under the bf16 noise already present.
__device__ __forceinline__ float gelu_f(float x) {
    float x2 = x * x;
    float inner = fmaf(0.044715f * x, x2, x);
    float t = exp2f(inner * -2.302089214f);   // 2^(-2*0.7978845608*log2(e)*inner)
    return x / (1.0f + t);
}

// ---- bf16 storage helpers (compute stays fp32) ----
__device__ __forceinline__ float bf2f(ushort_t h) {
    return __uint_as_float(((unsigned int)h) << 16);
}
__device__ __forceinline__ ushort_t f2bf(float f) {
    unsigned int u = __float_as_uint(f);
    u += 0x7FFFu + ((u >> 16) & 1u);   // round to nearest even
    return (ushort_t)(u >> 16);
}
struct us4 { ushort_t x, y, z, w; };

__device__ __forceinline__ void st4(ushort_t* p, float4 v) {
    us4 h; h.x = f2bf(v.x); h.y = f2bf(v.y); h.z = f2bf(v.z); h.w = f2bf(v.w);
    *(us4*)p = h;
}

// ---------------- twiddle step table for k_f2 / k_i1
__global__ void k_fill_tw(float* __restrict__ ct, float* __restrict__ st) {
    int j = blockIdx.x * 256 + threadIdx.x;   // 0..1023
    float ang = (float)j * (6.283185307179586f / 1024.0f);
    float s, c;
    sincosf(ang, &s, &c);
    ct[j] = c; st[j] = s;
}

// ---------------- T1 table: T1[k2p][y], [2k2][y]=cos(2pi k2 y/1024), [2k2+1][y]=-sin, hi/lo split
__global__ void k_fill_T1(ushort_t* __restrict__ T1h, ushort_t* __restrict__ T1l) {
    int idx = blockIdx.x * 256 + threadIdx.x;   // 0..65535
    int k2p = idx >> 10, y = idx & 1023;
    int k2 = k2p >> 1;
    float ang = (float)((k2 * y) & MASKN) * (6.283185307179586f / 1024.0f);
    float s, c;
    sincosf(ang, &s, &c);
    float v = (k2p & 1) ? -s : c;
    ushort_t h = f2bf(v);
    T1h[idx] = h;
    T1l[idx] = f2bf(v - bf2f(h));
}

// ---------------- T2 table: T2[n2][kk], [n2][2k2]=cos(2pi n2 k2/1024), [n2][2k2+1]=-sin, hi/lo
__global__ void k_fill_T2(ushort_t* __restrict__ T2h, ushort_t* __restrict__ T2l) {
    int idx = blockIdx.x * 256 + threadIdx.x;   // 0..65535
    int n2 = idx >> 6, kk = idx & 63;
    int k2 = kk >> 1;
    float ang = (float)((k2 * n2) & MASKN) * (6.283185307179586f / 1024.0f);
    float s, c;
    sincosf(ang, &s, &c);
    float v = (kk & 1) ? -s : c;
    ushort_t h = f2bf(v);
    T2h[idx] = h;
    T2l[idx] = f2bf(v - bf2f(h));
}

// ---------------- wT tables: wT[l][d][c] = w_l[c][d], hi/lo
__global__ void k_fill_wT(const float* __restrict__ w1, const float* __restrict__ w2,
        const float* __restrict__ w3, const float* __restrict__ w4,
        ushort_t* __restrict__ wTh, ushort_t* __restrict__ wTl) {
    int l = blockIdx.y;
    int i = blockIdx.x * 256 + threadIdx.x;   // 0..4095
    int d = i >> 6, c = i & 63;
    const float* w = (l == 0) ? w1 : (l == 1) ? w2 : (l == 2) ? w3 : w4;
    float v = w[c * 64 + d];
    ushort_t h = f2bf(v);
    wTh[l * 4096 + i] = h;
    wTl[l * 4096 + i] = f2bf(v - bf2f(h));
}

// ---------------- shallow: vt[p][c] = gelu(in[p][0]*Wsh[0][c] + in[p][1]*Wsh[1][c] + bsh[c])
__global__ __launch_bounds__(256) void k_shallow(const float* __restrict__ in,
        const float* __restrict__ Wsh, const float* __restrict__ bsh,
        ushort_t* __restrict__ vt) {
    int tid = blockIdx.x * 256 + threadIdx.x;
    int p = tid >> 4, c0 = (tid & 15) << 2;
    float a0 = in[p * 2], a1 = in[p * 2 + 1];
    float4 w0 = *(const float4*)&Wsh[c0];
    float4 w1 = *(const float4*)&Wsh[64 + c0];
    float4 b  = *(const float4*)&bsh[c0];
    float4 r;
    r.x = gelu_f(fmaf(a0, w0.x, fmaf(a1, w1.x, b.x)));
    r.y = gelu_f(fmaf(a0, w0.y, fmaf(a1, w1.y, b.y)));
    r.z = gelu_f(fmaf(a0, w0.z, fmaf(a1, w1.z, b.z)));
    r.w = gelu_f(fmaf(a0, w0.w, fmaf(a1, w1.w, b.w)));
    st4(&vt[(size_t)p * 64 + c0], r);
}

// ---------------- F1 (MFMA): gT[x][c][k2p] = sum_y vt[x][y][c] * T1[k2p][y]
// block = one x; double-buffered LDS transpose, register prefetch of next chunk,
// single barrier per chunk.
#define F1S 136   // LDS row stride (bf16) for transposed vt tile
__global__ __launch_bounds__(256) void k_f1(const ushort_t* __restrict__ vt,
        const ushort_t* __restrict__ T1h, const ushort_t* __restrict__ T1l,
        float* __restrict__ gT) {
    __shared__ __align__(16) ushort_t vs[2][64 * F1S];   // 2 x 17408 B
    int t = threadIdx.x;
    int x = blockIdx.x;
    int wv = t >> 6, ln = t & 63;
    int lm = ln & 15, quad = ln >> 4;
    int mt = wv;                          // wave's m-tile (16 c rows)
    int lrow = t & 127, chalf = (t >> 7) * 32;   // staging map
    floatx4 acc[4];
    #pragma unroll
    for (int nt = 0; nt < 4; ++nt) acc[nt] = (floatx4)(0.f);
    const ushort_t* vrow = vt + (size_t)x * 65536;
    uint4 pf[4];
    {
        const ushort_t* src = vrow + (size_t)lrow * 64 + chalf;
        #pragma unroll
        for (int i = 0; i < 4; ++i) pf[i] = *(const uint4*)(src + i * 8);
    }
    for (int ch = 0; ch < 8; ++ch) {
        ushort_t* vsb = vs[ch & 1];
        // scatter staged registers transposed into LDS: vs[c][y]
        #pragma unroll
        for (int i = 0; i < 4; ++i) {
            union { uint4 u; ushort_t e[8]; } uv;
            uv.u = pf[i];
            #pragma unroll
            for (int j = 0; j < 8; ++j)
                vsb[(chalf + i * 8 + j) * F1S + lrow] = uv.e[j];
        }
        // prefetch next chunk (overlaps barrier + MFMA below)
        if (ch < 7) {
            const ushort_t* src = vrow + (size_t)((ch + 1) * 128 + lrow) * 64 + chalf;
            #pragma unroll
            for (int i = 0; i < 4; ++i) pf[i] = *(const uint4*)(src + i * 8);
        }
        __syncthreads();
        #pragma unroll
        for (int ks = 0; ks < 4; ++ks) {
            short8 af = *(const short8*)&vsb[(mt * 16 + lm) * F1S + ks * 32 + quad * 8];
            int ybase = ch * 128 + ks * 32 + quad * 8;
            #pragma unroll
            for (int nt = 0; nt < 4; ++nt) {
                short8 bh = *(const short8*)(T1h + (size_t)(nt * 16 + lm) * 1024 + ybase);
                short8 bl = *(const short8*)(T1l + (size_t)(nt * 16 + lm) * 1024 + ybase);
                acc[nt] = __builtin_amdgcn_mfma_f32_16x16x32_bf16(af, bh, acc[nt], 0, 0, 0);
                acc[nt] = __builtin_amdgcn_mfma_f32_16x16x32_bf16(af, bl, acc[nt], 0, 0, 0);
            }
        }
    }
    float* grow = gT + (size_t)x * 4096;
    #pragma unroll
    for (int nt = 0; nt < 4; ++nt)
        #pragma unroll
        for (int r = 0; r < 4; ++r)
            grow[(mt * 16 + quad * 4 + r) * 64 + nt * 16 + lm] = acc[nt][r];
}

// ---------------- F2: fp[cx][k1*32+k2][c] = sum_{x in cx} g[x][k2][c] (x) e^{-2pi i k1 x/1024}
// grid (8 cx, 16 cg, 4 k1-groups)
__global__ __launch_bounds__(256) void k_f2(const float* __restrict__ gT,
        const float* __restrict__ ct, const float* __restrict__ st,
        float* __restrict__ fpr, float* __restrict__ fpi) {
    int t = threadIdx.x;
    int cx = blockIdx.x;          // 0..7
    int cg = blockIdx.y;          // 0..15
    int k10 = blockIdx.z * 8;     // 0,8,16,24
    int l = t & 63;               // k2p
    int q = t >> 6;               // 0..3
    int c = cg * 4 + q;
    int e = l & 1;                // 0 = re lane, 1 = im lane
    int k2 = l >> 1;
    float acc[8];
    #pragma unroll
    for (int i = 0; i < 8; ++i) acc[i] = 0.f;
    for (int xi = 0; xi < 128; ++xi) {
        int x = cx * 128 + xi;
        float v = gT[(size_t)x * 4096 + c * 64 + l];
        float p = __shfl_xor(v, 1);
        float gr = e ? p : v;
        float gi = e ? v : p;
        float u  = e ? gi : gr;
        float w2 = e ? -gr : gi;
        float cb = ct[x], sb = st[x];
        int ph = (x * k10) & MASKN;
        float cr = ct[ph], sr = st[ph];
        #pragma unroll
        for (int j = 0; j < 8; ++j) {
            acc[j] = fmaf(u, cr, fmaf(w2, sr, acc[j]));
            float nc = fmaf(cr, cb, -sr * sb);
            float ns = fmaf(sr, cb, cr * sb);
            cr = nc; sr = ns;
        }
    }
    float* dst = e ? fpi : fpr;
    #pragma unroll
    for (int j = 0; j < 8; ++j)
        dst[(size_t)cx * 65536 + ((k10 + j) * 32 + k2) * 64 + c] = acc[j];
}

// ---------------- MIX: Rf[m,d] = sum_c f[m,c] * (Rr+iRi)[m,c,d], f = sum of 8 partials
__global__ __launch_bounds__(64) void k_mix(const float* __restrict__ fpr, const float* __restrict__ fpi,
        const float* __restrict__ Rr, const float* __restrict__ Ri,
        float* __restrict__ Rfr, float* __restrict__ Rfi) {
    __shared__ float fr[64], fi[64];
    int m = blockIdx.x;
    int d = threadIdx.x;
    float sr = 0.f, si = 0.f;
    #pragma unroll
    for (int ch = 0; ch < 8; ++ch) {
        sr += fpr[(size_t)ch * 65536 + m * 64 + d];
        si += fpi[(size_t)ch * 65536 + m * 64 + d];
    }
    fr[d] = sr; fi[d] = si;
    __syncthreads();
    const float* Rrb = Rr + (size_t)m * 4096;
    const float* Rib = Ri + (size_t)m * 4096;
    float ar = 0.f, ai = 0.f;
    for (int c = 0; c < 64; ++c) {
        float rr = Rrb[c * 64 + d], ri = Rib[c * 64 + d];
        ar = fmaf(fr[c], rr, fmaf(-fi[c], ri, ar));
        ai = fmaf(fr[c], ri, fmaf(fi[c], rr, ai));
    }
    Rfr[m * 64 + d] = ar;
    Rfi[m * 64 + d] = ai;
}

// ---------------- I1: Bmat[n1][d][kk] (bf16 hi/lo, kk = 2k2(+1) = re/im interleaved)
__global__ __launch_bounds__(256) void k_i1(const float* __restrict__ Rfr, const float* __restrict__ Rfi,
        const float* __restrict__ ctg, const float* __restrict__ stg,
        ushort_t* __restrict__ Bh, ushort_t* __restrict__ Bl) {
    __shared__ float ct[1024], st[1024];
    int t = threadIdx.x;
    #pragma unroll
    for (int i = 0; i < 4; ++i) { int j = t + 256 * i; ct[j] = ctg[j]; st[j] = stg[j]; }
    __syncthreads();
    int n1 = blockIdx.x;
    int d = t & 63;
    int k20 = (t >> 6) * 8;
    float br[8], bi[8];
    #pragma unroll
    for (int j = 0; j < 8; ++j) { br[j] = 0.f; bi[j] = 0.f; }
    int idx = 0;
    for (int k1 = 0; k1 < 32; ++k1) {
        float cc = ct[idx], ss = st[idx];
        idx = (idx + n1) & MASKN;
        #pragma unroll
        for (int j = 0; j < 8; ++j) {
            float rr = Rfr[(k1 * 32 + k20 + j) * 64 + d];
            float ri = Rfi[(k1 * 32 + k20 + j) * 64 + d];
            br[j] = fmaf(rr, cc, fmaf(-ri, ss, br[j]));
            bi[j] = fmaf(rr, ss, fmaf(ri, cc, bi[j]));
        }
    }
    union { uint4 u[2]; ushort_t e[16]; } hh, ll;
    #pragma unroll
    for (int j = 0; j < 8; ++j) {
        int k2 = k20 + j;
        float sc = (k2 == 0 ? 1.0f : 2.0f) * 9.5367431640625e-7f;   // 1/2^20
        float vr = br[j] * sc, vi = bi[j] * sc;
        ushort_t hr = f2bf(vr), hi2 = f2bf(vi);
        hh.e[2 * j] = hr;          hh.e[2 * j + 1] = hi2;
        ll.e[2 * j] = f2bf(vr - bf2f(hr));
        ll.e[2 * j + 1] = f2bf(vi - bf2f(hi2));
    }
    size_t base = ((size_t)n1 * 64 + d) * 64 + 2 * k20;
    *(uint4*)(Bh + base) = hh.u[0];
    *(uint4*)(Bh + base + 8) = hh.u[1];
    *(uint4*)(Bl + base) = ll.u[0];
    *(uint4*)(Bl + base + 8) = ll.u[1];
}

// ---------------- I2 (MFMA, fused skip+inverse): vt[n1][n2][d] = gelu( T2[n2,:]@Bmat[n1][:, d] + vt[n1][n2,:]@w[:,d] )
// A-side = Bmat/wT (rows = d), B-side = T2/vt (rows = n2); C-layout gives each
// thread 4 CONTIGUOUS d per fragment -> 8x 8-byte stores.
// Round-2 change: the compiler's max-occupancy scheduler serialized loads
// (VGPR_Count=56 -> one load in flight; MfmaUtil 9.5%, HBM 18%, latency-bound).
// Force load clustering with explicit named buffers + sched_group_barrier (T19):
//   C1: 24 VMEM_READ -> M1: 24 MFMA -> C2: 12 VMEM_READ -> M2: 24 MFMA
//   -> C3: 8 VMEM_READ -> M3/M4: 32 MFMA -> epilogue.
// Peak live regs ~144+addr; __launch_bounds__(256,3) caps at 170 (3 waves/SIMD).
// grid (8 n2-chunks, 1024 n1); 4 waves; no LDS, no barriers.
// FINAL=true: fuse the output projection (out = gelu(.)@Wp + bp), skip the vt store.
template<bool FINAL>
__global__ __launch_bounds__(256, 3) void k_i2(ushort_t* __restrict__ vt,
        const ushort_t* __restrict__ Bh, const ushort_t* __restrict__ Bl,
        const ushort_t* __restrict__ T2h, const ushort_t* __restrict__ T2l,
        const ushort_t* __restrict__ wTh, const ushort_t* __restrict__ wTl,
        const float* __restrict__ Wp, const float* __restrict__ bp,
        float* __restrict__ out) {
    int t = threadIdx.x;
    int wv = t >> 6, ln = t & 63;
    int lm = ln & 15, quad = ln >> 4;
    int chunk = blockIdx.x, n1 = blockIdx.y;
    int n2b = chunk * 128 + wv * 32;
    const ushort_t* Bhr = Bh + (size_t)n1 * 4096;
    const ushort_t* Blr = Bl + (size_t)n1 * 4096;
    ushort_t* vrow = vt + ((size_t)n1 * 1024 + n2b) * 64;
    int kk0 = quad * 8;           // phase-1/2 k-offset, ks=0
    int kk1 = 32 + quad * 8;      // ks=1

    // ---------- C1: 24 VMEM_READ: vt skip (HBM, longest latency, first),
    // phase-1 ks0 operands, and Bmat ks1 A-side ----------
    short8 v0[2][2];
    #pragma unroll
    for (int ks = 0; ks < 2; ++ks)
        #pragma unroll
        for (int nt = 0; nt < 2; ++nt)
            v0[ks][nt] = *(const short8*)(vrow + (size_t)(nt * 16 + lm) * 64 + ks * 32 + quad * 8);
    short8 th0[2], tl0[2];
    #pragma unroll
    for (int nt = 0; nt < 2; ++nt) {
        th0[nt] = *(const short8*)(T2h + (size_t)(n2b + nt * 16 + lm) * 64 + kk0);
        tl0[nt] = *(const short8*)(T2l + (size_t)(n2b + nt * 16 + lm) * 64 + kk0);
    }
    short8 ah0[4], al0[4], ah1[4], al1[4];
    #pragma unroll
    for (int mt = 0; mt < 4; ++mt) {
        ah0[mt] = *(const short8*)(Bhr + (size_t)(mt * 16 + lm) * 64 + kk0);
        al0[mt] = *(const short8*)(Blr + (size_t)(mt * 16 + lm) * 64 + kk0);
        ah1[mt] = *(const short8*)(Bhr + (size_t)(mt * 16 + lm) * 64 + kk1);
        al1[mt] = *(const short8*)(Blr + (size_t)(mt * 16 + lm) * 64 + kk1);
    }
    __builtin_amdgcn_sched_group_barrier(0x20, 24, 0);   // VMEM_READ x24

    floatx4 acc[4][2];   // [d-tile][n2-tile]
    #pragma unroll
    for (int mt = 0; mt < 4; ++mt)
        #pragma unroll
        for (int nt = 0; nt < 2; ++nt) acc[mt][nt] = (floatx4)(0.f);

    // ---------- M1: phase-1 ks0 (hh + lh + hl), 24 MFMA ----------
    #pragma unroll
    for (int mt = 0; mt < 4; ++mt)
        #pragma unroll
        for (int nt = 0; nt < 2; ++nt) {
            acc[mt][nt] = __builtin_amdgcn_mfma_f32_16x16x32_bf16(ah0[mt], th0[nt], acc[mt][nt], 0, 0, 0);
            acc[mt][nt] = __builtin_amdgcn_mfma_f32_16x16x32_bf16(al0[mt], th0[nt], acc[mt][nt], 0, 0, 0);
            acc[mt][nt] = __builtin_amdgcn_mfma_f32_16x16x32_bf16(ah0[mt], tl0[nt], acc[mt][nt], 0, 0, 0);
        }
    __builtin_amdgcn_sched_group_barrier(0x8, 24, 0);    // MFMA x24

    // ---------- C2: 12 VMEM_READ: T2 ks1 + wT ks0 ----------
    short8 th1[2], tl1[2];
    #pragma unroll
    for (int nt = 0; nt < 2; ++nt) {
        th1[nt] = *(const short8*)(T2h + (size_t)(n2b + nt * 16 + lm) * 64 + kk1);
        tl1[nt] = *(const short8*)(T2l + (size_t)(n2b + nt * 16 + lm) * 64 + kk1);
    }
    short8 wh0[4], wl0[4];
    #pragma unroll
    for (int mt = 0; mt < 4; ++mt) {
        wh0[mt] = *(const short8*)(wTh + (mt * 16 + lm) * 64 + kk0);
        wl0[mt] = *(const short8*)(wTl + (mt * 16 + lm) * 64 + kk0);
    }
    __builtin_amdgcn_sched_group_barrier(0x20, 12, 0);   // VMEM_READ x12

    // ---------- M2: phase-1 ks1, 24 MFMA ----------
    #pragma unroll
    for (int mt = 0; mt < 4; ++mt)
        #pragma unroll
        for (int nt = 0; nt < 2; ++nt) {
            acc[mt][nt] = __builtin_amdgcn_mfma_f32_16x16x32_bf16(ah1[mt], th1[nt], acc[mt][nt], 0, 0, 0);
            acc[mt][nt] = __builtin_amdgcn_mfma_f32_16x16x32_bf16(al1[mt], th1[nt], acc[mt][nt], 0, 0, 0);
            acc[mt][nt] = __builtin_amdgcn_mfma_f32_16x16x32_bf16(ah1[mt], tl1[nt], acc[mt][nt], 0, 0, 0);
        }
    __builtin_amdgcn_sched_group_barrier(0x8, 24, 0);    // MFMA x24

    // ---------- C3: 8 VMEM_READ: wT ks1 ----------
    short8 wh1[4], wl1[4];
    #pragma unroll
    for (int mt = 0; mt < 4; ++mt) {
        wh1[mt] = *(const short8*)(wTh + (mt * 16 + lm) * 64 + kk1);
        wl1[mt] = *(const short8*)(wTl + (mt * 16 + lm) * 64 + kk1);
    }
    __builtin_amdgcn_sched_group_barrier(0x20, 8, 0);    // VMEM_READ x8

    // ---------- M3+M4: phase-2 (skip connection), 32 MFMA ----------
    #pragma unroll
    for (int mt = 0; mt < 4; ++mt)
        #pragma unroll
        for (int nt = 0; nt < 2; ++nt) {
            acc[mt][nt] = __builtin_amdgcn_mfma_f32_16x16x32_bf16(wh0[mt], v0[0][nt], acc[mt][nt], 0, 0, 0);
            acc[mt][nt] = __builtin_amdgcn_mfma_f32_16x16x32_bf16(wl0[mt], v0[0][nt], acc[mt][nt], 0, 0, 0);
            acc[mt][nt] = __builtin_amdgcn_mfma_f32_16x16x32_bf16(wh1[mt], v0[1][nt], acc[mt][nt], 0, 0, 0);
            acc[mt][nt] = __builtin_amdgcn_mfma_f32_16x16x32_bf16(wl1[mt], v0[1][nt], acc[mt][nt], 0, 0, 0);
        }
    __builtin_amdgcn_sched_group_barrier(0x8, 32, 0);    // MFMA x32

    if (!FINAL) {
        // epilogue: gelu + bf16; thread owns d = mt*16 + quad*4 + r (contiguous r)
        // at n2 = n2b + nt*16 + lm  ->  8x 8-byte stores.
        #pragma unroll
        for (int nt = 0; nt < 2; ++nt) {
            size_t rowoff = (size_t)(nt * 16 + lm) * 64;
            #pragma unroll
            for (int mt = 0; mt < 4; ++mt) {
                us4v h;
                h.x = f2bf(gelu_f(acc[mt][nt][0]));
                h.y = f2bf(gelu_f(acc[mt][nt][1]));
                h.z = f2bf(gelu_f(acc[mt][nt][2]));
                h.w = f2bf(gelu_f(acc[mt][nt][3]));
                *(us4v*)(vrow + rowoff + mt * 16 + quad * 4) = h;
            }
        }
    } else {
        // fused projection: out[n1][n2] = sum_d gelu(acc) * Wp[d] + bp.
        // thread holds 16 d-values per nt; reduce the 4 quads with shfl_xor.
        float bp0 = bp[0];
        #pragma unroll
        for (int nt = 0; nt < 2; ++nt) {
            float s = 0.f;
            #pragma unroll
            for (int mt = 0; mt < 4; ++mt) {
                float4 wp = *(const float4*)&Wp[mt * 16 + quad * 4];
                s = fmaf(gelu_f(acc[mt][nt][0]), wp.x, s);
                s = fmaf(gelu_f(acc[mt][nt][1]), wp.y, s);
                s = fmaf(gelu_f(acc[mt][nt][2]), wp.z, s);
                s = fmaf(gelu_f(acc[mt][nt][3]), wp.w, s);
            }
            s += __shfl_xor(s, 16);
            s += __shfl_xor(s, 32);
            if (quad == 0)
                out[(size_t)n1 * 1024 + n2b + nt * 16 + lm] = s + bp0;
        }
    }
}

extern "C" void kernel_launch(void* const* d_in, const int* in_sizes, int n_in,
                              void* d_out, int out_size, void* d_ws, size_t ws_size,
                              hipStream_t stream) {
    const float* in  = (const float*)d_in[0];
    const float* Wsh = (const float*)d_in[1];
    const float* bsh = (const float*)d_in[2];
    const float* Wp  = (const float*)d_in[15];
    const float* bp  = (const float*)d_in[16];

    // workspace layout (~151.9 MB, proven to fit)
    char* wsb = (char*)d_ws;
    ushort_t* vt   = (ushort_t*)wsb;                          // 1024*1024*64 bf16 = 134,217,728 B
    float* ctab = (float*)(wsb + 134217728);                  // 1024
    float* stab = ctab + 1024;                                // 1024
    float* gT   = stab + 1024;                                // 1024*64*64 f32 = 16 MB
    float* Rfr  = gT + 4194304;                               // 65536
    float* Rfi  = Rfr + 65536;                                // 65536
    ushort_t* T1h = (ushort_t*)(Rfi + 65536);                 // 64*1024
    ushort_t* T1l = T1h + 65536;
    ushort_t* T2h = T1l + 65536;                              // 1024*64
    ushort_t* T2l = T2h + 65536;
    ushort_t* wTh = T2l + 65536;                              // 4*64*64
    ushort_t* wTl = wTh + 16384;
    ushort_t* Bh  = (ushort_t*)gT;                            // alias gT (dead after k_f2)
    ushort_t* Bl  = Bh + 4194304;
    float* fpr = (float*)d_out;                               // alias d_out (dead before final k_i2)
    float* fpi = fpr + 524288;

    k_fill_tw<<<4, 256, 0, stream>>>(ctab, stab);
    k_fill_T1<<<256, 256, 0, stream>>>(T1h, T1l);
    k_fill_T2<<<256, 256, 0, stream>>>(T2h, T2l);
    k_fill_wT<<<dim3(16, 4), 256, 0, stream>>>((const float*)d_in[5], (const float*)d_in[8],
                                               (const float*)d_in[11], (const float*)d_in[14], wTh, wTl);
    k_shallow<<<65536, 256, 0, stream>>>(in, Wsh, bsh, vt);
    for (int L = 0; L < 4; ++L) {
        const float* Rr = (const float*)d_in[3 + L * 3];
        const float* Ri = (const float*)d_in[4 + L * 3];
        k_f1<<<1024, 256, 0, stream>>>(vt, T1h, T1l, gT);
        k_f2<<<dim3(8, 16, 4), 256, 0, stream>>>(gT, ctab, stab, fpr, fpi);
        k_mix<<<1024, 64, 0, stream>>>(fpr, fpi, Rr, Ri, Rfr, Rfi);
        k_i1<<<1024, 256, 0, stream>>>(Rfr, Rfi, ctab, stab, Bh, Bl);
        if (L < 3) {
            k_i2<false><<<dim3(8, 1024), 256, 0, stream>>>(vt, Bh, Bl, T2h, T2l,
                    wTh + L * 4096, wTl + L * 4096, nullptr, nullptr, nullptr);
        } else {
            // final layer: fuse projection, write d_out directly (fp partials in
            // d_out are dead after k_mix); vt is never stored again.
            k_i2<true><<<dim3(8, 1024), 256, 0, stream>>>(vt, Bh, Bl, T2h, T2l,
                    wTh + L * 4096, wTl + L * 4096, Wp, bp, (float*)d_out);
        }
    }
}

// Round 3
// 1203.209 us; speedup vs baseline: 1.2890x; 1.2680x over previous
//
#include <hip/hip_runtime.h>
#include <math.h>

#define MASKN 1023

typedef unsigned short ushort_t;
typedef __attribute__((ext_vector_type(8))) short short8;
typedef __attribute__((ext_vector_type(4))) float floatx4;
typedef __attribute__((ext_vector_type(4))) unsigned short us4v;   // 8B-aligned bf16x4

// tanh-form GELU as x * sigmoid(2*0.7978845608*(x + 0.044715 x^3)); one v_exp_f32.
__device__ __forceinline__ float gelu_f(float x) {
    float x2 = x * x;
    float inner = fmaf(0.044715f * x, x2, x);
    float t = exp2f(inner * -2.302089214f);
    return x / (1.0f + t);
}

// ---- bf16 storage helpers (compute stays fp32) ----
__device__ __forceinline__ float bf2f(ushort_t h) {
    return __uint_as_float(((unsigned int)h) << 16);
}
__device__ __forceinline__ ushort_t f2bf(float f) {
    unsigned int u = __float_as_uint(f);
    u += 0x7FFFu + ((u >> 16) & 1u);   // round to nearest even
    return (ushort_t)(u >> 16);
}
struct us4 { ushort_t x, y, z, w; };

__device__ __forceinline__ void st4(ushort_t* p, float4 v) {
    us4 h; h.x = f2bf(v.x); h.y = f2bf(v.y); h.z = f2bf(v.z); h.w = f2bf(v.w);
    *(us4*)p = h;
}

// async global->LDS, 16 B per lane; LDS dest = wave-uniform base + lane*16 (HW),
// global src is PER-LANE (this is how the swizzled staging works).
__device__ __forceinline__ void async16(ushort_t* l, const ushort_t* g) {
    __builtin_amdgcn_global_load_lds(
        (const __attribute__((address_space(1))) void*)g,
        (__attribute__((address_space(3))) void*)l, 16, 0, 0);
}

// ---------------- twiddle step table for k_f2 / k_i1
__global__ void k_fill_tw(float* __restrict__ ct, float* __restrict__ st) {
    int j = blockIdx.x * 256 + threadIdx.x;   // 0..1023
    float ang = (float)j * (6.283185307179586f / 1024.0f);
    float s, c;
    sincosf(ang, &s, &c);
    ct[j] = c; st[j] = s;
}

// ---------------- T1 table
__global__ void k_fill_T1(ushort_t* __restrict__ T1h, ushort_t* __restrict__ T1l) {
    int idx = blockIdx.x * 256 + threadIdx.x;   // 0..65535
    int k2p = idx >> 10, y = idx & 1023;
    int k2 = k2p >> 1;
    float ang = (float)((k2 * y) & MASKN) * (6.283185307179586f / 1024.0f);
    float s, c;
    sincosf(ang, &s, &c);
    float v = (k2p & 1) ? -s : c;
    ushort_t h = f2bf(v);
    T1h[idx] = h;
    T1l[idx] = f2bf(v - bf2f(h));
}

// ---------------- T2 table: T2[n2][kk]
__global__ void k_fill_T2(ushort_t* __restrict__ T2h, ushort_t* __restrict__ T2l) {
    int idx = blockIdx.x * 256 + threadIdx.x;   // 0..65535
    int n2 = idx >> 6, kk = idx & 63;
    int k2 = kk >> 1;
    float ang = (float)((k2 * n2) & MASKN) * (6.283185307179586f / 1024.0f);
    float s, c;
    sincosf(ang, &s, &c);
    float v = (kk & 1) ? -s : c;
    ushort_t h = f2bf(v);
    T2h[idx] = h;
    T2l[idx] = f2bf(v - bf2f(h));
}

// ---------------- wT tables: wT[l][d][c] = w_l[c][d], hi/lo
__global__ void k_fill_wT(const float* __restrict__ w1, const float* __restrict__ w2,
        const float* __restrict__ w3, const float* __restrict__ w4,
        ushort_t* __restrict__ wTh, ushort_t* __restrict__ wTl) {
    int l = blockIdx.y;
    int i = blockIdx.x * 256 + threadIdx.x;   // 0..4095
    int d = i >> 6, c = i & 63;
    const float* w = (l == 0) ? w1 : (l == 1) ? w2 : (l == 2) ? w3 : w4;
    float v = w[c * 64 + d];
    ushort_t h = f2bf(v);
    wTh[l * 4096 + i] = h;
    wTl[l * 4096 + i] = f2bf(v - bf2f(h));
}

// ---------------- shallow
__global__ __launch_bounds__(256) void k_shallow(const float* __restrict__ in,
        const float* __restrict__ Wsh, const float* __restrict__ bsh,
        ushort_t* __restrict__ vt) {
    int tid = blockIdx.x * 256 + threadIdx.x;
    int p = tid >> 4, c0 = (tid & 15) << 2;
    float a0 = in[p * 2], a1 = in[p * 2 + 1];
    float4 w0 = *(const float4*)&Wsh[c0];
    float4 w1 = *(const float4*)&Wsh[64 + c0];
    float4 b  = *(const float4*)&bsh[c0];
    float4 r;
    r.x = gelu_f(fmaf(a0, w0.x, fmaf(a1, w1.x, b.x)));
    r.y = gelu_f(fmaf(a0, w0.y, fmaf(a1, w1.y, b.y)));
    r.z = gelu_f(fmaf(a0, w0.z, fmaf(a1, w1.z, b.z)));
    r.w = gelu_f(fmaf(a0, w0.w, fmaf(a1, w1.w, b.w)));
    st4(&vt[(size_t)p * 64 + c0], r);
}

// ---------------- F1 (MFMA): gT[x][c][k2p] = sum_y vt[x][y][c] * T1[k2p][y]
#define F1S 136
__global__ __launch_bounds__(256) void k_f1(const ushort_t* __restrict__ vt,
        const ushort_t* __restrict__ T1h, const ushort_t* __restrict__ T1l,
        float* __restrict__ gT) {
    __shared__ __align__(16) ushort_t vs[2][64 * F1S];
    int t = threadIdx.x;
    int x = blockIdx.x;
    int wv = t >> 6, ln = t & 63;
    int lm = ln & 15, quad = ln >> 4;
    int mt = wv;
    int lrow = t & 127, chalf = (t >> 7) * 32;
    floatx4 acc[4];
    #pragma unroll
    for (int nt = 0; nt < 4; ++nt) acc[nt] = (floatx4)(0.f);
    const ushort_t* vrow = vt + (size_t)x * 65536;
    uint4 pf[4];
    {
        const ushort_t* src = vrow + (size_t)lrow * 64 + chalf;
        #pragma unroll
        for (int i = 0; i < 4; ++i) pf[i] = *(const uint4*)(src + i * 8);
    }
    for (int ch = 0; ch < 8; ++ch) {
        ushort_t* vsb = vs[ch & 1];
        #pragma unroll
        for (int i = 0; i < 4; ++i) {
            union { uint4 u; ushort_t e[8]; } uv;
            uv.u = pf[i];
            #pragma unroll
            for (int j = 0; j < 8; ++j)
                vsb[(chalf + i * 8 + j) * F1S + lrow] = uv.e[j];
        }
        if (ch < 7) {
            const ushort_t* src = vrow + (size_t)((ch + 1) * 128 + lrow) * 64 + chalf;
            #pragma unroll
            for (int i = 0; i < 4; ++i) pf[i] = *(const uint4*)(src + i * 8);
        }
        __syncthreads();
        #pragma unroll
        for (int ks = 0; ks < 4; ++ks) {
            short8 af = *(const short8*)&vsb[(mt * 16 + lm) * F1S + ks * 32 + quad * 8];
            int ybase = ch * 128 + ks * 32 + quad * 8;
            #pragma unroll
            for (int nt = 0; nt < 4; ++nt) {
                short8 bh = *(const short8*)(T1h + (size_t)(nt * 16 + lm) * 1024 + ybase);
                short8 bl = *(const short8*)(T1l + (size_t)(nt * 16 + lm) * 1024 + ybase);
                acc[nt] = __builtin_amdgcn_mfma_f32_16x16x32_bf16(af, bh, acc[nt], 0, 0, 0);
                acc[nt] = __builtin_amdgcn_mfma_f32_16x16x32_bf16(af, bl, acc[nt], 0, 0, 0);
            }
        }
    }
    float* grow = gT + (size_t)x * 4096;
    #pragma unroll
    for (int nt = 0; nt < 4; ++nt)
        #pragma unroll
        for (int r = 0; r < 4; ++r)
            grow[(mt * 16 + quad * 4 + r) * 64 + nt * 16 + lm] = acc[nt][r];
}

// ---------------- F2
__global__ __launch_bounds__(256) void k_f2(const float* __restrict__ gT,
        const float* __restrict__ ct, const float* __restrict__ st,
        float* __restrict__ fpr, float* __restrict__ fpi) {
    int t = threadIdx.x;
    int cx = blockIdx.x;
    int cg = blockIdx.y;
    int k10 = blockIdx.z * 8;
    int l = t & 63;
    int q = t >> 6;
    int c = cg * 4 + q;
    int e = l & 1;
    int k2 = l >> 1;
    float acc[8];
    #pragma unroll
    for (int i = 0; i < 8; ++i) acc[i] = 0.f;
    for (int xi = 0; xi < 128; ++xi) {
        int x = cx * 128 + xi;
        float v = gT[(size_t)x * 4096 + c * 64 + l];
        float p = __shfl_xor(v, 1);
        float gr = e ? p : v;
        float gi = e ? v : p;
        float u  = e ? gi : gr;
        float w2 = e ? -gr : gi;
        float cb = ct[x], sb = st[x];
        int ph = (x * k10) & MASKN;
        float cr = ct[ph], sr = st[ph];
        #pragma unroll
        for (int j = 0; j < 8; ++j) {
            acc[j] = fmaf(u, cr, fmaf(w2, sr, acc[j]));
            float nc = fmaf(cr, cb, -sr * sb);
            float ns = fmaf(sr, cb, cr * sb);
            cr = nc; sr = ns;
        }
    }
    float* dst = e ? fpi : fpr;
    #pragma unroll
    for (int j = 0; j < 8; ++j)
        dst[(size_t)cx * 65536 + ((k10 + j) * 32 + k2) * 64 + c] = acc[j];
}

// ---------------- MIX
__global__ __launch_bounds__(64) void k_mix(const float* __restrict__ fpr, const float* __restrict__ fpi,
        const float* __restrict__ Rr, const float* __restrict__ Ri,
        float* __restrict__ Rfr, float* __restrict__ Rfi) {
    __shared__ float fr[64], fi[64];
    int m = blockIdx.x;
    int d = threadIdx.x;
    float sr = 0.f, si = 0.f;
    #pragma unroll
    for (int ch = 0; ch < 8; ++ch) {
        sr += fpr[(size_t)ch * 65536 + m * 64 + d];
        si += fpi[(size_t)ch * 65536 + m * 64 + d];
    }
    fr[d] = sr; fi[d] = si;
    __syncthreads();
    const float* Rrb = Rr + (size_t)m * 4096;
    const float* Rib = Ri + (size_t)m * 4096;
    float ar = 0.f, ai = 0.f;
    for (int c = 0; c < 64; ++c) {
        float rr = Rrb[c * 64 + d], ri = Rib[c * 64 + d];
        ar = fmaf(fr[c], rr, fmaf(-fi[c], ri, ar));
        ai = fmaf(fr[c], ri, fmaf(fi[c], rr, ai));
    }
    Rfr[m * 64 + d] = ar;
    Rfi[m * 64 + d] = ai;
}

// ---------------- I1: Bmat[n1][d][kk]
__global__ __launch_bounds__(256) void k_i1(const float* __restrict__ Rfr, const float* __restrict__ Rfi,
        const float* __restrict__ ctg, const float* __restrict__ stg,
        ushort_t* __restrict__ Bh, ushort_t* __restrict__ Bl) {
    __shared__ float ct[1024], st[1024];
    int t = threadIdx.x;
    #pragma unroll
    for (int i = 0; i < 4; ++i) { int j = t + 256 * i; ct[j] = ctg[j]; st[j] = stg[j]; }
    __syncthreads();
    int n1 = blockIdx.x;
    int d = t & 63;
    int k20 = (t >> 6) * 8;
    float br[8], bi[8];
    #pragma unroll
    for (int j = 0; j < 8; ++j) { br[j] = 0.f; bi[j] = 0.f; }
    int idx = 0;
    for (int k1 = 0; k1 < 32; ++k1) {
        float cc = ct[idx], ss = st[idx];
        idx = (idx + n1) & MASKN;
        #pragma unroll
        for (int j = 0; j < 8; ++j) {
            float rr = Rfr[(k1 * 32 + k20 + j) * 64 + d];
            float ri = Rfi[(k1 * 32 + k20 + j) * 64 + d];
            br[j] = fmaf(rr, cc, fmaf(-ri, ss, br[j]));
            bi[j] = fmaf(rr, ss, fmaf(ri, cc, bi[j]));
        }
    }
    union { uint4 u[2]; ushort_t e[16]; } hh, ll;
    #pragma unroll
    for (int j = 0; j < 8; ++j) {
        int k2 = k20 + j;
        float sc = (k2 == 0 ? 1.0f : 2.0f) * 9.5367431640625e-7f;   // 1/2^20
        float vr = br[j] * sc, vi = bi[j] * sc;
        ushort_t hr = f2bf(vr), hi2 = f2bf(vi);
        hh.e[2 * j] = hr;          hh.e[2 * j + 1] = hi2;
        ll.e[2 * j] = f2bf(vr - bf2f(hr));
        ll.e[2 * j + 1] = f2bf(vi - bf2f(hi2));
    }
    size_t base = ((size_t)n1 * 64 + d) * 64 + 2 * k20;
    *(uint4*)(Bh + base) = hh.u[0];
    *(uint4*)(Bh + base + 8) = hh.u[1];
    *(uint4*)(Bl + base) = ll.u[0];
    *(uint4*)(Bl + base + 8) = ll.u[1];
}

// ---------------- I2 (MFMA, fused skip+inverse), round-3 restructure.
// Diagnosis R0-R2: 184 us constant = 44 serialized global loads x ~930 cy per
// wave (B/T2 thrashed out of L2 by the 268 MB vt stream; scheduler never holds
// >4-7 loads in flight from registers). Fix the MECHANISM:
//  - block = one n1 (1024 blocks), loops all 8 n2-chunks -> B(n1)+wT loaded
//    ONCE per block into LDS then registers (was 8x global re-reads).
//  - T2 chunk double-buffered in LDS via global_load_lds (zero-VGPR in-flight
//    loads): stage T2[c+1] + prefetch vt[c+1] regs while computing chunk c;
//    one __syncthreads per chunk (prefetch issued a full chunk early -> drain free).
//  - T2 staged with XOR-swizzled SOURCE (LDS dest linear, rule both-sides):
//    16-B unit u of row r lands at slot u^(r&7) -> fragment ds_reads spread
//    across all 32 banks (row-stride-128B reads would be 16-way conflicted).
// LDS 64 KB -> 2 blocks/CU; VGPR ~230 (acc32+B64+wT64+v32+frags).
template<bool FINAL, int C>
__device__ __forceinline__ void i2_chunk(
        short8 (&VC)[2][2], short8 (&VN)[2][2],
        ushort_t* bufC, ushort_t* bufN,
        const ushort_t* __restrict__ T2h_g, const ushort_t* __restrict__ T2l_g,
        ushort_t* __restrict__ vt, float* __restrict__ out,
        const short8 (&ah0)[4], const short8 (&al0)[4],
        const short8 (&ah1)[4], const short8 (&al1)[4],
        const short8 (&wh0)[4], const short8 (&wl0)[4],
        const short8 (&wh1)[4], const short8 (&wl1)[4],
        const float4 (&wpv)[4], float bp0,
        int n1, int wv, int lane, int lm, int quad) {
    // ---- prefetch next chunk: T2[C+1] -> bufN (async, swizzled src), vt[C+1] -> VN
    if (C < 7) {
        #pragma unroll
        for (int i = 0; i < 8; ++i) {
            int j = wv * 512 + i * 64 + lane;          // 0..2047 16B-units
            int jh = j & 1023;
            int r = jh >> 3, u = (jh & 7) ^ (r & 7);   // inverse swizzle on SOURCE
            const ushort_t* src = (wv < 2 ? T2h_g : T2l_g)
                                  + (size_t)(C + 1) * 8192 + r * 64 + u * 8;
            async16(&bufN[wv * 4096 + i * 512], src);
        }
        const ushort_t* vnext = vt + ((size_t)n1 * 1024 + (C + 1) * 128 + wv * 32) * 64;
        #pragma unroll
        for (int ks = 0; ks < 2; ++ks)
            #pragma unroll
            for (int nt = 0; nt < 2; ++nt)
                VN[ks][nt] = *(const short8*)(vnext + (size_t)(nt * 16 + lm) * 64 + ks * 32 + quad * 8);
    }
    __builtin_amdgcn_sched_barrier(0);   // pin prefetch issue above the compute

    floatx4 acc[4][2];
    #pragma unroll
    for (int mt = 0; mt < 4; ++mt)
        #pragma unroll
        for (int nt = 0; nt < 2; ++nt) acc[mt][nt] = (floatx4)(0.f);

    // ---- phase 1 ks=0: T2 frags from LDS (swizzled slots), 24 MFMA
    {
        short8 th[2], tl[2];
        int sl = quad ^ (lm & 7);
        #pragma unroll
        for (int nt = 0; nt < 2; ++nt) {
            int rr = wv * 32 + nt * 16 + lm;
            th[nt] = *(const short8*)&bufC[rr * 64 + sl * 8];
            tl[nt] = *(const short8*)&bufC[8192 + rr * 64 + sl * 8];
        }
        #pragma unroll
        for (int mt = 0; mt < 4; ++mt)
            #pragma unroll
            for (int nt = 0; nt < 2; ++nt) {
                acc[mt][nt] = __builtin_amdgcn_mfma_f32_16x16x32_bf16(ah0[mt], th[nt], acc[mt][nt], 0, 0, 0);
                acc[mt][nt] = __builtin_amdgcn_mfma_f32_16x16x32_bf16(al0[mt], th[nt], acc[mt][nt], 0, 0, 0);
                acc[mt][nt] = __builtin_amdgcn_mfma_f32_16x16x32_bf16(ah0[mt], tl[nt], acc[mt][nt], 0, 0, 0);
            }
    }
    // ---- phase 1 ks=1
    {
        short8 th[2], tl[2];
        int sl = (4 + quad) ^ (lm & 7);
        #pragma unroll
        for (int nt = 0; nt < 2; ++nt) {
            int rr = wv * 32 + nt * 16 + lm;
            th[nt] = *(const short8*)&bufC[rr * 64 + sl * 8];
            tl[nt] = *(const short8*)&bufC[8192 + rr * 64 + sl * 8];
        }
        #pragma unroll
        for (int mt = 0; mt < 4; ++mt)
            #pragma unroll
            for (int nt = 0; nt < 2; ++nt) {
                acc[mt][nt] = __builtin_amdgcn_mfma_f32_16x16x32_bf16(ah1[mt], th[nt], acc[mt][nt], 0, 0, 0);
                acc[mt][nt] = __builtin_amdgcn_mfma_f32_16x16x32_bf16(al1[mt], th[nt], acc[mt][nt], 0, 0, 0);
                acc[mt][nt] = __builtin_amdgcn_mfma_f32_16x16x32_bf16(ah1[mt], tl[nt], acc[mt][nt], 0, 0, 0);
            }
    }
    // ---- phase 2: skip connection, all operands in regs, 32 MFMA
    #pragma unroll
    for (int mt = 0; mt < 4; ++mt)
        #pragma unroll
        for (int nt = 0; nt < 2; ++nt) {
            acc[mt][nt] = __builtin_amdgcn_mfma_f32_16x16x32_bf16(wh0[mt], VC[0][nt], acc[mt][nt], 0, 0, 0);
            acc[mt][nt] = __builtin_amdgcn_mfma_f32_16x16x32_bf16(wl0[mt], VC[0][nt], acc[mt][nt], 0, 0, 0);
            acc[mt][nt] = __builtin_amdgcn_mfma_f32_16x16x32_bf16(wh1[mt], VC[1][nt], acc[mt][nt], 0, 0, 0);
            acc[mt][nt] = __builtin_amdgcn_mfma_f32_16x16x32_bf16(wl1[mt], VC[1][nt], acc[mt][nt], 0, 0, 0);
        }

    if (!FINAL) {
        ushort_t* vrow = vt + ((size_t)n1 * 1024 + C * 128 + wv * 32) * 64;
        #pragma unroll
        for (int nt = 0; nt < 2; ++nt) {
            size_t rowoff = (size_t)(nt * 16 + lm) * 64;
            #pragma unroll
            for (int mt = 0; mt < 4; ++mt) {
                us4v h;
                h.x = f2bf(gelu_f(acc[mt][nt][0]));
                h.y = f2bf(gelu_f(acc[mt][nt][1]));
                h.z = f2bf(gelu_f(acc[mt][nt][2]));
                h.w = f2bf(gelu_f(acc[mt][nt][3]));
                *(us4v*)(vrow + rowoff + mt * 16 + quad * 4) = h;
            }
        }
    } else {
        #pragma unroll
        for (int nt = 0; nt < 2; ++nt) {
            float s = 0.f;
            #pragma unroll
            for (int mt = 0; mt < 4; ++mt) {
                s = fmaf(gelu_f(acc[mt][nt][0]), wpv[mt].x, s);
                s = fmaf(gelu_f(acc[mt][nt][1]), wpv[mt].y, s);
                s = fmaf(gelu_f(acc[mt][nt][2]), wpv[mt].z, s);
                s = fmaf(gelu_f(acc[mt][nt][3]), wpv[mt].w, s);
            }
            s += __shfl_xor(s, 16);
            s += __shfl_xor(s, 32);
            if (quad == 0)
                out[(size_t)n1 * 1024 + C * 128 + wv * 32 + nt * 16 + lm] = s + bp0;
        }
    }
    if (C < 7) __syncthreads();   // T2[C+1]/vt[C+1] issued a chunk ago -> drain ~free
}

template<bool FINAL>
__global__ __launch_bounds__(256, 2) void k_i2(ushort_t* __restrict__ vt,
        const ushort_t* __restrict__ Bh, const ushort_t* __restrict__ Bl,
        const ushort_t* __restrict__ T2h, const ushort_t* __restrict__ T2l,
        const ushort_t* __restrict__ wTh, const ushort_t* __restrict__ wTl,
        const float* __restrict__ Wp, const float* __restrict__ bp,
        float* __restrict__ out) {
    __shared__ __align__(16) ushort_t lds[2][16384];   // 2 x 32 KB
    int t = threadIdx.x;
    int wv = t >> 6, lane = t & 63;
    int lm = lane & 15, quad = lane >> 4;
    int n1 = blockIdx.x;
    const ushort_t* Bhr = Bh + (size_t)n1 * 4096;
    const ushort_t* Blr = Bl + (size_t)n1 * 4096;

    // ---- prologue staging: T2[0] -> lds[0] (swizzled), B+wT -> lds[1] (linear)
    #pragma unroll
    for (int i = 0; i < 8; ++i) {
        int j = wv * 512 + i * 64 + lane;
        int jh = j & 1023;
        int r = jh >> 3, u = (jh & 7) ^ (r & 7);
        const ushort_t* src = (wv < 2 ? T2h : T2l) + (size_t)r * 64 + u * 8;   // chunk 0
        async16(&lds[0][wv * 4096 + i * 512], src);
    }
    {
        const ushort_t* s = (wv == 0) ? Bhr : (wv == 1) ? Blr : (wv == 2) ? wTh : wTl;
        #pragma unroll
        for (int i = 0; i < 8; ++i)
            async16(&lds[1][wv * 4096 + i * 512], s + i * 512 + lane * 8);
    }
    short8 vA[2][2], vB[2][2];
    {
        const ushort_t* v0p = vt + ((size_t)n1 * 1024 + wv * 32) * 64;
        #pragma unroll
        for (int ks = 0; ks < 2; ++ks)
            #pragma unroll
            for (int nt = 0; nt < 2; ++nt)
                vA[ks][nt] = *(const short8*)(v0p + (size_t)(nt * 16 + lm) * 64 + ks * 32 + quad * 8);
    }
    __syncthreads();

    // ---- B + wT fragments -> registers (once per block; 16-way-conflict reads
    // but only 32 of them, amortized over 8 chunks)
    short8 ah0[4], al0[4], ah1[4], al1[4], wh0[4], wl0[4], wh1[4], wl1[4];
    #pragma unroll
    for (int mt = 0; mt < 4; ++mt) {
        int ro = (mt * 16 + lm) * 64 + quad * 8;
        ah0[mt] = *(const short8*)&lds[1][ro];
        ah1[mt] = *(const short8*)&lds[1][ro + 32];
        al0[mt] = *(const short8*)&lds[1][4096 + ro];
        al1[mt] = *(const short8*)&lds[1][4096 + ro + 32];
        wh0[mt] = *(const short8*)&lds[1][8192 + ro];
        wh1[mt] = *(const short8*)&lds[1][8192 + ro + 32];
        wl0[mt] = *(const short8*)&lds[1][12288 + ro];
        wl1[mt] = *(const short8*)&lds[1][12288 + ro + 32];
    }
    float4 wpv[4];
    float bp0 = 0.f;
    if (FINAL) {
        bp0 = bp[0];
        #pragma unroll
        for (int mt = 0; mt < 4; ++mt) wpv[mt] = *(const float4*)&Wp[mt * 16 + quad * 4];
    }
    __syncthreads();   // lds[1] now free for T2[1]

    #define I2CALL(c, VCUR, VNXT, BCUR, BNXT) \
        i2_chunk<FINAL, c>(VCUR, VNXT, BCUR, BNXT, T2h, T2l, vt, out, \
                           ah0, al0, ah1, al1, wh0, wl0, wh1, wl1, wpv, bp0, \
                           n1, wv, lane, lm, quad)
    I2CALL(0, vA, vB, lds[0], lds[1]);
    I2CALL(1, vB, vA, lds[1], lds[0]);
    I2CALL(2, vA, vB, lds[0], lds[1]);
    I2CALL(3, vB, vA, lds[1], lds[0]);
    I2CALL(4, vA, vB, lds[0], lds[1]);
    I2CALL(5, vB, vA, lds[1], lds[0]);
    I2CALL(6, vA, vB, lds[0], lds[1]);
    I2CALL(7, vB, vA, lds[1], lds[0]);
    #undef I2CALL
}

extern "C" void kernel_launch(void* const* d_in, const int* in_sizes, int n_in,
                              void* d_out, int out_size, void* d_ws, size_t ws_size,
                              hipStream_t stream) {
    const float* in  = (const float*)d_in[0];
    const float* Wsh = (const float*)d_in[1];
    const float* bsh = (const float*)d_in[2];
    const float* Wp  = (const float*)d_in[15];
    const float* bp  = (const float*)d_in[16];

    // workspace layout (~151.9 MB, proven to fit)
    char* wsb = (char*)d_ws;
    ushort_t* vt   = (ushort_t*)wsb;                          // 1024*1024*64 bf16 = 134,217,728 B
    float* ctab = (float*)(wsb + 134217728);                  // 1024
    float* stab = ctab + 1024;                                // 1024
    float* gT   = stab + 1024;                                // 1024*64*64 f32 = 16 MB
    float* Rfr  = gT + 4194304;                               // 65536
    float* Rfi  = Rfr + 65536;                                // 65536
    ushort_t* T1h = (ushort_t*)(Rfi + 65536);                 // 64*1024
    ushort_t* T1l = T1h + 65536;
    ushort_t* T2h = T1l + 65536;                              // 1024*64
    ushort_t* T2l = T2h + 65536;
    ushort_t* wTh = T2l + 65536;                              // 4*64*64
    ushort_t* wTl = wTh + 16384;
    ushort_t* Bh  = (ushort_t*)gT;                            // alias gT (dead after k_f2)
    ushort_t* Bl  = Bh + 4194304;
    float* fpr = (float*)d_out;                               // alias d_out (dead before final k_i2)
    float* fpi = fpr + 524288;

    k_fill_tw<<<4, 256, 0, stream>>>(ctab, stab);
    k_fill_T1<<<256, 256, 0, stream>>>(T1h, T1l);
    k_fill_T2<<<256, 256, 0, stream>>>(T2h, T2l);
    k_fill_wT<<<dim3(16, 4), 256, 0, stream>>>((const float*)d_in[5], (const float*)d_in[8],
                                               (const float*)d_in[11], (const float*)d_in[14], wTh, wTl);
    k_shallow<<<65536, 256, 0, stream>>>(in, Wsh, bsh, vt);
    for (int L = 0; L < 4; ++L) {
        const float* Rr = (const float*)d_in[3 + L * 3];
        const float* Ri = (const float*)d_in[4 + L * 3];
        k_f1<<<1024, 256, 0, stream>>>(vt, T1h, T1l, gT);
        k_f2<<<dim3(8, 16, 4), 256, 0, stream>>>(gT, ctab, stab, fpr, fpi);
        k_mix<<<1024, 64, 0, stream>>>(fpr, fpi, Rr, Ri, Rfr, Rfi);
        k_i1<<<1024, 256, 0, stream>>>(Rfr, Rfi, ctab, stab, Bh, Bl);
        if (L < 3) {
            k_i2<false><<<1024, 256, 0, stream>>>(vt, Bh, Bl, T2h, T2l,
                    wTh + L * 4096, wTl + L * 4096, nullptr, nullptr, nullptr);
        } else {
            k_i2<true><<<1024, 256, 0, stream>>>(vt, Bh, Bl, T2h, T2l,
                    wTh + L * 4096, wTl + L * 4096, Wp, bp, (float*)d_out);
        }
    }
}

// Round 4
// 902.969 us; speedup vs baseline: 1.7176x; 1.3325x over previous
//
#include <hip/hip_runtime.h>
#include <math.h>

#define MASKN 1023

typedef unsigned short ushort_t;
typedef __attribute__((ext_vector_type(8))) short short8;
typedef __attribute__((ext_vector_type(4))) float floatx4;
typedef __attribute__((ext_vector_type(4))) unsigned short us4v;   // 8B-aligned bf16x4

// tanh-form GELU as x * sigmoid(2*0.7978845608*(x + 0.044715 x^3)); one v_exp_f32.
__device__ __forceinline__ float gelu_f(float x) {
    float x2 = x * x;
    float inner = fmaf(0.044715f * x, x2, x);
    float t = exp2f(inner * -2.302089214f);
    return x / (1.0f + t);
}

// ---- bf16 storage helpers (compute stays fp32) ----
__device__ __forceinline__ float bf2f(ushort_t h) {
    return __uint_as_float(((unsigned int)h) << 16);
}
__device__ __forceinline__ ushort_t f2bf(float f) {
    unsigned int u = __float_as_uint(f);
    u += 0x7FFFu + ((u >> 16) & 1u);   // round to nearest even
    return (ushort_t)(u >> 16);
}
struct us4 { ushort_t x, y, z, w; };

__device__ __forceinline__ void st4(ushort_t* p, float4 v) {
    us4 h; h.x = f2bf(v.x); h.y = f2bf(v.y); h.z = f2bf(v.z); h.w = f2bf(v.w);
    *(us4*)p = h;
}

// async global->LDS, 16 B per lane; LDS dest = wave-uniform base + lane*16 (HW),
// global src is PER-LANE (this is how the swizzled staging works).
__device__ __forceinline__ void async16(ushort_t* l, const ushort_t* g) {
    __builtin_amdgcn_global_load_lds(
        (const __attribute__((address_space(1))) void*)g,
        (__attribute__((address_space(3))) void*)l, 16, 0, 0);
}

// ---------------- twiddle step table for k_f2 / k_i1
__global__ void k_fill_tw(float* __restrict__ ct, float* __restrict__ st) {
    int j = blockIdx.x * 256 + threadIdx.x;   // 0..1023
    float ang = (float)j * (6.283185307179586f / 1024.0f);
    float s, c;
    sincosf(ang, &s, &c);
    ct[j] = c; st[j] = s;
}

// ---------------- T1 table
__global__ void k_fill_T1(ushort_t* __restrict__ T1h, ushort_t* __restrict__ T1l) {
    int idx = blockIdx.x * 256 + threadIdx.x;   // 0..65535
    int k2p = idx >> 10, y = idx & 1023;
    int k2 = k2p >> 1;
    float ang = (float)((k2 * y) & MASKN) * (6.283185307179586f / 1024.0f);
    float s, c;
    sincosf(ang, &s, &c);
    float v = (k2p & 1) ? -s : c;
    ushort_t h = f2bf(v);
    T1h[idx] = h;
    T1l[idx] = f2bf(v - bf2f(h));
}

// ---------------- T2 table: T2[n2][kk]
__global__ void k_fill_T2(ushort_t* __restrict__ T2h, ushort_t* __restrict__ T2l) {
    int idx = blockIdx.x * 256 + threadIdx.x;   // 0..65535
    int n2 = idx >> 6, kk = idx & 63;
    int k2 = kk >> 1;
    float ang = (float)((k2 * n2) & MASKN) * (6.283185307179586f / 1024.0f);
    float s, c;
    sincosf(ang, &s, &c);
    float v = (kk & 1) ? -s : c;
    ushort_t h = f2bf(v);
    T2h[idx] = h;
    T2l[idx] = f2bf(v - bf2f(h));
}

// ---------------- wT tables: wT[l][d][c] = w_l[c][d], hi/lo
__global__ void k_fill_wT(const float* __restrict__ w1, const float* __restrict__ w2,
        const float* __restrict__ w3, const float* __restrict__ w4,
        ushort_t* __restrict__ wTh, ushort_t* __restrict__ wTl) {
    int l = blockIdx.y;
    int i = blockIdx.x * 256 + threadIdx.x;   // 0..4095
    int d = i >> 6, c = i & 63;
    const float* w = (l == 0) ? w1 : (l == 1) ? w2 : (l == 2) ? w3 : w4;
    float v = w[c * 64 + d];
    ushort_t h = f2bf(v);
    wTh[l * 4096 + i] = h;
    wTl[l * 4096 + i] = f2bf(v - bf2f(h));
}

// ---------------- shallow
__global__ __launch_bounds__(256) void k_shallow(const float* __restrict__ in,
        const float* __restrict__ Wsh, const float* __restrict__ bsh,
        ushort_t* __restrict__ vt) {
    int tid = blockIdx.x * 256 + threadIdx.x;
    int p = tid >> 4, c0 = (tid & 15) << 2;
    float a0 = in[p * 2], a1 = in[p * 2 + 1];
    float4 w0 = *(const float4*)&Wsh[c0];
    float4 w1 = *(const float4*)&Wsh[64 + c0];
    float4 b  = *(const float4*)&bsh[c0];
    float4 r;
    r.x = gelu_f(fmaf(a0, w0.x, fmaf(a1, w1.x, b.x)));
    r.y = gelu_f(fmaf(a0, w0.y, fmaf(a1, w1.y, b.y)));
    r.z = gelu_f(fmaf(a0, w0.z, fmaf(a1, w1.z, b.z)));
    r.w = gelu_f(fmaf(a0, w0.w, fmaf(a1, w1.w, b.w)));
    st4(&vt[(size_t)p * 64 + c0], r);
}

// ---------------- F1 (MFMA): gT[x][c][k2p] = sum_y vt[x][y][c] * T1[k2p][y]
// Round-4 restructure. Old version read T1 from GLOBAL inside the MFMA loop:
// 256 short8 loads/thread at VGPR_Count=56 -> serialized at L2 latency
// (MfmaUtil 4.9%, VALUBusy 3.0%, HBM 8% -- all idle). Same cure as k_i2:
//  - 16 half-chunks of y=64; T1 tile (64 k2p x 64 y, hi+lo = 16 KB) staged into
//    double-buffered LDS via global_load_lds (zero-VGPR in-flight loads).
//  - T1 staged with XOR-swizzled SOURCE (LDS dest linear): 16B-unit u of row r
//    lands at slot u^(r&7) -> fragment ds_read_b128 (row stride 128 B, otherwise
//    16-way same-bank) spreads across all banks.
//  - vt tile scatter-transposed into LDS (stride 72 shorts = 2-way-free banks),
//    double-buffered; pf regs loaded one half-chunk ahead.
//  - ONE __syncthreads per half-chunk; next-tile loads issued right AFTER it so
//    they get a full compute phase before the next barrier's vmcnt drain.
// LDS = 2x16KB (T1) + 2x9KB (vs) = 50 KB -> 3 blocks/CU.
#define VS1 72   // vs row stride in shorts (144 B -> bank 4*lm, 2-way = free)
__global__ __launch_bounds__(256, 3) void k_f1(const ushort_t* __restrict__ vt,
        const ushort_t* __restrict__ T1h, const ushort_t* __restrict__ T1l,
        float* __restrict__ gT) {
    __shared__ __align__(16) ushort_t t1s[2][8192];      // [buf][h:0..4095 | l:4096..8191] shorts
    __shared__ __align__(16) ushort_t vs[2][64 * VS1];   // [buf][c][y] transposed vt tile
    int t = threadIdx.x;
    int x = blockIdx.x;
    int wv = t >> 6, lane = t & 63;
    int lm = lane & 15, quad = lane >> 4;
    int lrow = t & 63, cq = (t >> 6) * 16;               // staging map: 64 y-rows x 4 c-quarters
    const ushort_t* vrow = vt + (size_t)x * 65536;

    floatx4 acc[4];
    #pragma unroll
    for (int nt = 0; nt < 4; ++nt) acc[nt] = (floatx4)(0.f);

    uint4 pf[2];
    // prologue: T1[0] stage + vt[0] regs
    {
        #pragma unroll
        for (int i = 0; i < 4; ++i) {
            int j = (wv * 4 + i) * 64 + lane;            // 0..1023 16B-units (h then l)
            int jj = j & 511;
            int r = jj >> 3, du = jj & 7, su = du ^ (r & 7);
            const ushort_t* src = ((j < 512) ? T1h : T1l) + (size_t)r * 1024 + su * 8;
            async16(&t1s[0][(wv * 4 + i) * 512], src);
        }
        const ushort_t* srcv = vrow + (size_t)lrow * 64 + cq;
        pf[0] = *(const uint4*)(srcv);
        pf[1] = *(const uint4*)(srcv + 8);
    }

    for (int hc = 0; hc < 16; ++hc) {
        int b = hc & 1;
        // scatter pf(hc) transposed into vs[b] (waits pf regs; vmcnt-drains older too)
        #pragma unroll
        for (int i = 0; i < 2; ++i) {
            union { uint4 u; ushort_t e[8]; } uv;
            uv.u = pf[i];
            #pragma unroll
            for (int j = 0; j < 8; ++j)
                vs[b][(cq + i * 8 + j) * VS1 + lrow] = uv.e[j];
        }
        __syncthreads();   // t1s[b] staged (issued one phase ago) + vs[b] visible

        if (hc < 15) {
            // issue next-tile loads NOW: a full MFMA phase before next barrier drain
            const ushort_t* srcv = vrow + (size_t)((hc + 1) * 64 + lrow) * 64 + cq;
            pf[0] = *(const uint4*)(srcv);
            pf[1] = *(const uint4*)(srcv + 8);
            #pragma unroll
            for (int i = 0; i < 4; ++i) {
                int j = (wv * 4 + i) * 64 + lane;
                int jj = j & 511;
                int r = jj >> 3, du = jj & 7, su = du ^ (r & 7);
                const ushort_t* src = ((j < 512) ? T1h : T1l)
                                      + (size_t)r * 1024 + (hc + 1) * 64 + su * 8;
                async16(&t1s[b ^ 1][(wv * 4 + i) * 512], src);
            }
        }
        __builtin_amdgcn_sched_barrier(0);   // pin load issue above the MFMA cluster

        #pragma unroll
        for (int ys = 0; ys < 2; ++ys) {
            short8 af = *(const short8*)&vs[b][(wv * 16 + lm) * VS1 + ys * 32 + quad * 8];
            #pragma unroll
            for (int nt = 0; nt < 4; ++nt) {
                int sl = (((ys * 4 + quad) ^ (lm & 7)) * 8);   // swizzled 16B slot (shorts)
                short8 bh = *(const short8*)&t1s[b][(nt * 16 + lm) * 64 + sl];
                short8 bl = *(const short8*)&t1s[b][4096 + (nt * 16 + lm) * 64 + sl];
                acc[nt] = __builtin_amdgcn_mfma_f32_16x16x32_bf16(af, bh, acc[nt], 0, 0, 0);
                acc[nt] = __builtin_amdgcn_mfma_f32_16x16x32_bf16(af, bl, acc[nt], 0, 0, 0);
            }
        }
    }
    float* grow = gT + (size_t)x * 4096;
    #pragma unroll
    for (int nt = 0; nt < 4; ++nt)
        #pragma unroll
        for (int r = 0; r < 4; ++r)
            grow[(wv * 16 + quad * 4 + r) * 64 + nt * 16 + lm] = acc[nt][r];
}

// ---------------- F2
__global__ __launch_bounds__(256) void k_f2(const float* __restrict__ gT,
        const float* __restrict__ ct, const float* __restrict__ st,
        float* __restrict__ fpr, float* __restrict__ fpi) {
    int t = threadIdx.x;
    int cx = blockIdx.x;
    int cg = blockIdx.y;
    int k10 = blockIdx.z * 8;
    int l = t & 63;
    int q = t >> 6;
    int c = cg * 4 + q;
    int e = l & 1;
    int k2 = l >> 1;
    float acc[8];
    #pragma unroll
    for (int i = 0; i < 8; ++i) acc[i] = 0.f;
    for (int xi = 0; xi < 128; ++xi) {
        int x = cx * 128 + xi;
        float v = gT[(size_t)x * 4096 + c * 64 + l];
        float p = __shfl_xor(v, 1);
        float gr = e ? p : v;
        float gi = e ? v : p;
        float u  = e ? gi : gr;
        float w2 = e ? -gr : gi;
        float cb = ct[x], sb = st[x];
        int ph = (x * k10) & MASKN;
        float cr = ct[ph], sr = st[ph];
        #pragma unroll
        for (int j = 0; j < 8; ++j) {
            acc[j] = fmaf(u, cr, fmaf(w2, sr, acc[j]));
            float nc = fmaf(cr, cb, -sr * sb);
            float ns = fmaf(sr, cb, cr * sb);
            cr = nc; sr = ns;
        }
    }
    float* dst = e ? fpi : fpr;
    #pragma unroll
    for (int j = 0; j < 8; ++j)
        dst[(size_t)cx * 65536 + ((k10 + j) * 32 + k2) * 64 + c] = acc[j];
}

// ---------------- MIX
__global__ __launch_bounds__(64) void k_mix(const float* __restrict__ fpr, const float* __restrict__ fpi,
        const float* __restrict__ Rr, const float* __restrict__ Ri,
        float* __restrict__ Rfr, float* __restrict__ Rfi) {
    __shared__ float fr[64], fi[64];
    int m = blockIdx.x;
    int d = threadIdx.x;
    float sr = 0.f, si = 0.f;
    #pragma unroll
    for (int ch = 0; ch < 8; ++ch) {
        sr += fpr[(size_t)ch * 65536 + m * 64 + d];
        si += fpi[(size_t)ch * 65536 + m * 64 + d];
    }
    fr[d] = sr; fi[d] = si;
    __syncthreads();
    const float* Rrb = Rr + (size_t)m * 4096;
    const float* Rib = Ri + (size_t)m * 4096;
    float ar = 0.f, ai = 0.f;
    for (int c = 0; c < 64; ++c) {
        float rr = Rrb[c * 64 + d], ri = Rib[c * 64 + d];
        ar = fmaf(fr[c], rr, fmaf(-fi[c], ri, ar));
        ai = fmaf(fr[c], ri, fmaf(fi[c], rr, ai));
    }
    Rfr[m * 64 + d] = ar;
    Rfi[m * 64 + d] = ai;
}

// ---------------- I1: Bmat[n1][d][kk]
__global__ __launch_bounds__(256) void k_i1(const float* __restrict__ Rfr, const float* __restrict__ Rfi,
        const float* __restrict__ ctg, const float* __restrict__ stg,
        ushort_t* __restrict__ Bh, ushort_t* __restrict__ Bl) {
    __shared__ float ct[1024], st[1024];
    int t = threadIdx.x;
    #pragma unroll
    for (int i = 0; i < 4; ++i) { int j = t + 256 * i; ct[j] = ctg[j]; st[j] = stg[j]; }
    __syncthreads();
    int n1 = blockIdx.x;
    int d = t & 63;
    int k20 = (t >> 6) * 8;
    float br[8], bi[8];
    #pragma unroll
    for (int j = 0; j < 8; ++j) { br[j] = 0.f; bi[j] = 0.f; }
    int idx = 0;
    for (int k1 = 0; k1 < 32; ++k1) {
        float cc = ct[idx], ss = st[idx];
        idx = (idx + n1) & MASKN;
        #pragma unroll
        for (int j = 0; j < 8; ++j) {
            float rr = Rfr[(k1 * 32 + k20 + j) * 64 + d];
            float ri = Rfi[(k1 * 32 + k20 + j) * 64 + d];
            br[j] = fmaf(rr, cc, fmaf(-ri, ss, br[j]));
            bi[j] = fmaf(rr, ss, fmaf(ri, cc, bi[j]));
        }
    }
    union { uint4 u[2]; ushort_t e[16]; } hh, ll;
    #pragma unroll
    for (int j = 0; j < 8; ++j) {
        int k2 = k20 + j;
        float sc = (k2 == 0 ? 1.0f : 2.0f) * 9.5367431640625e-7f;   // 1/2^20
        float vr = br[j] * sc, vi = bi[j] * sc;
        ushort_t hr = f2bf(vr), hi2 = f2bf(vi);
        hh.e[2 * j] = hr;          hh.e[2 * j + 1] = hi2;
        ll.e[2 * j] = f2bf(vr - bf2f(hr));
        ll.e[2 * j + 1] = f2bf(vi - bf2f(hi2));
    }
    size_t base = ((size_t)n1 * 64 + d) * 64 + 2 * k20;
    *(uint4*)(Bh + base) = hh.u[0];
    *(uint4*)(Bh + base + 8) = hh.u[1];
    *(uint4*)(Bl + base) = ll.u[0];
    *(uint4*)(Bl + base + 8) = ll.u[1];
}

// ---------------- I2 (MFMA, fused skip+inverse), round-3 structure (unchanged).
template<bool FINAL, int C>
__device__ __forceinline__ void i2_chunk(
        short8 (&VC)[2][2], short8 (&VN)[2][2],
        ushort_t* bufC, ushort_t* bufN,
        const ushort_t* __restrict__ T2h_g, const ushort_t* __restrict__ T2l_g,
        ushort_t* __restrict__ vt, float* __restrict__ out,
        const short8 (&ah0)[4], const short8 (&al0)[4],
        const short8 (&ah1)[4], const short8 (&al1)[4],
        const short8 (&wh0)[4], const short8 (&wl0)[4],
        const short8 (&wh1)[4], const short8 (&wl1)[4],
        const float4 (&wpv)[4], float bp0,
        int n1, int wv, int lane, int lm, int quad) {
    // ---- prefetch next chunk: T2[C+1] -> bufN (async, swizzled src), vt[C+1] -> VN
    if (C < 7) {
        #pragma unroll
        for (int i = 0; i < 8; ++i) {
            int j = wv * 512 + i * 64 + lane;          // 0..2047 16B-units
            int jh = j & 1023;
            int r = jh >> 3, u = (jh & 7) ^ (r & 7);   // inverse swizzle on SOURCE
            const ushort_t* src = (wv < 2 ? T2h_g : T2l_g)
                                  + (size_t)(C + 1) * 8192 + r * 64 + u * 8;
            async16(&bufN[wv * 4096 + i * 512], src);
        }
        const ushort_t* vnext = vt + ((size_t)n1 * 1024 + (C + 1) * 128 + wv * 32) * 64;
        #pragma unroll
        for (int ks = 0; ks < 2; ++ks)
            #pragma unroll
            for (int nt = 0; nt < 2; ++nt)
                VN[ks][nt] = *(const short8*)(vnext + (size_t)(nt * 16 + lm) * 64 + ks * 32 + quad * 8);
    }
    __builtin_amdgcn_sched_barrier(0);   // pin prefetch issue above the compute

    floatx4 acc[4][2];
    #pragma unroll
    for (int mt = 0; mt < 4; ++mt)
        #pragma unroll
        for (int nt = 0; nt < 2; ++nt) acc[mt][nt] = (floatx4)(0.f);

    // ---- phase 1 ks=0: T2 frags from LDS (swizzled slots), 24 MFMA
    {
        short8 th[2], tl[2];
        int sl = quad ^ (lm & 7);
        #pragma unroll
        for (int nt = 0; nt < 2; ++nt) {
            int rr = wv * 32 + nt * 16 + lm;
            th[nt] = *(const short8*)&bufC[rr * 64 + sl * 8];
            tl[nt] = *(const short8*)&bufC[8192 + rr * 64 + sl * 8];
        }
        #pragma unroll
        for (int mt = 0; mt < 4; ++mt)
            #pragma unroll
            for (int nt = 0; nt < 2; ++nt) {
                acc[mt][nt] = __builtin_amdgcn_mfma_f32_16x16x32_bf16(ah0[mt], th[nt], acc[mt][nt], 0, 0, 0);
                acc[mt][nt] = __builtin_amdgcn_mfma_f32_16x16x32_bf16(al0[mt], th[nt], acc[mt][nt], 0, 0, 0);
                acc[mt][nt] = __builtin_amdgcn_mfma_f32_16x16x32_bf16(ah0[mt], tl[nt], acc[mt][nt], 0, 0, 0);
            }
    }
    // ---- phase 1 ks=1
    {
        short8 th[2], tl[2];
        int sl = (4 + quad) ^ (lm & 7);
        #pragma unroll
        for (int nt = 0; nt < 2; ++nt) {
            int rr = wv * 32 + nt * 16 + lm;
            th[nt] = *(const short8*)&bufC[rr * 64 + sl * 8];
            tl[nt] = *(const short8*)&bufC[8192 + rr * 64 + sl * 8];
        }
        #pragma unroll
        for (int mt = 0; mt < 4; ++mt)
            #pragma unroll
            for (int nt = 0; nt < 2; ++nt) {
                acc[mt][nt] = __builtin_amdgcn_mfma_f32_16x16x32_bf16(ah1[mt], th[nt], acc[mt][nt], 0, 0, 0);
                acc[mt][nt] = __builtin_amdgcn_mfma_f32_16x16x32_bf16(al1[mt], th[nt], acc[mt][nt], 0, 0, 0);
                acc[mt][nt] = __builtin_amdgcn_mfma_f32_16x16x32_bf16(ah1[mt], tl[nt], acc[mt][nt], 0, 0, 0);
            }
    }
    // ---- phase 2: skip connection, all operands in regs, 32 MFMA
    #pragma unroll
    for (int mt = 0; mt < 4; ++mt)
        #pragma unroll
        for (int nt = 0; nt < 2; ++nt) {
            acc[mt][nt] = __builtin_amdgcn_mfma_f32_16x16x32_bf16(wh0[mt], VC[0][nt], acc[mt][nt], 0, 0, 0);
            acc[mt][nt] = __builtin_amdgcn_mfma_f32_16x16x32_bf16(wl0[mt], VC[0][nt], acc[mt][nt], 0, 0, 0);
            acc[mt][nt] = __builtin_amdgcn_mfma_f32_16x16x32_bf16(wh1[mt], VC[1][nt], acc[mt][nt], 0, 0, 0);
            acc[mt][nt] = __builtin_amdgcn_mfma_f32_16x16x32_bf16(wl1[mt], VC[1][nt], acc[mt][nt], 0, 0, 0);
        }

    if (!FINAL) {
        ushort_t* vrow = vt + ((size_t)n1 * 1024 + C * 128 + wv * 32) * 64;
        #pragma unroll
        for (int nt = 0; nt < 2; ++nt) {
            size_t rowoff = (size_t)(nt * 16 + lm) * 64;
            #pragma unroll
            for (int mt = 0; mt < 4; ++mt) {
                us4v h;
                h.x = f2bf(gelu_f(acc[mt][nt][0]));
                h.y = f2bf(gelu_f(acc[mt][nt][1]));
                h.z = f2bf(gelu_f(acc[mt][nt][2]));
                h.w = f2bf(gelu_f(acc[mt][nt][3]));
                *(us4v*)(vrow + rowoff + mt * 16 + quad * 4) = h;
            }
        }
    } else {
        #pragma unroll
        for (int nt = 0; nt < 2; ++nt) {
            float s = 0.f;
            #pragma unroll
            for (int mt = 0; mt < 4; ++mt) {
                s = fmaf(gelu_f(acc[mt][nt][0]), wpv[mt].x, s);
                s = fmaf(gelu_f(acc[mt][nt][1]), wpv[mt].y, s);
                s = fmaf(gelu_f(acc[mt][nt][2]), wpv[mt].z, s);
                s = fmaf(gelu_f(acc[mt][nt][3]), wpv[mt].w, s);
            }
            s += __shfl_xor(s, 16);
            s += __shfl_xor(s, 32);
            if (quad == 0)
                out[(size_t)n1 * 1024 + C * 128 + wv * 32 + nt * 16 + lm] = s + bp0;
        }
    }
    if (C < 7) __syncthreads();   // T2[C+1]/vt[C+1] issued a chunk ago -> drain ~free
}

template<bool FINAL>
__global__ __launch_bounds__(256, 2) void k_i2(ushort_t* __restrict__ vt,
        const ushort_t* __restrict__ Bh, const ushort_t* __restrict__ Bl,
        const ushort_t* __restrict__ T2h, const ushort_t* __restrict__ T2l,
        const ushort_t* __restrict__ wTh, const ushort_t* __restrict__ wTl,
        const float* __restrict__ Wp, const float* __restrict__ bp,
        float* __restrict__ out) {
    __shared__ __align__(16) ushort_t lds[2][16384];   // 2 x 32 KB
    int t = threadIdx.x;
    int wv = t >> 6, lane = t & 63;
    int lm = lane & 15, quad = lane >> 4;
    int n1 = blockIdx.x;
    const ushort_t* Bhr = Bh + (size_t)n1 * 4096;
    const ushort_t* Blr = Bl + (size_t)n1 * 4096;

    // ---- prologue staging: T2[0] -> lds[0] (swizzled), B+wT -> lds[1] (linear)
    #pragma unroll
    for (int i = 0; i < 8; ++i) {
        int j = wv * 512 + i * 64 + lane;
        int jh = j & 1023;
        int r = jh >> 3, u = (jh & 7) ^ (r & 7);
        const ushort_t* src = (wv < 2 ? T2h : T2l) + (size_t)r * 64 + u * 8;   // chunk 0
        async16(&lds[0][wv * 4096 + i * 512], src);
    }
    {
        const ushort_t* s = (wv == 0) ? Bhr : (wv == 1) ? Blr : (wv == 2) ? wTh : wTl;
        #pragma unroll
        for (int i = 0; i < 8; ++i)
            async16(&lds[1][wv * 4096 + i * 512], s + i * 512 + lane * 8);
    }
    short8 vA[2][2], vB[2][2];
    {
        const ushort_t* v0p = vt + ((size_t)n1 * 1024 + wv * 32) * 64;
        #pragma unroll
        for (int ks = 0; ks < 2; ++ks)
            #pragma unroll
            for (int nt = 0; nt < 2; ++nt)
                vA[ks][nt] = *(const short8*)(v0p + (size_t)(nt * 16 + lm) * 64 + ks * 32 + quad * 8);
    }
    __syncthreads();

    // ---- B + wT fragments -> registers (once per block)
    short8 ah0[4], al0[4], ah1[4], al1[4], wh0[4], wl0[4], wh1[4], wl1[4];
    #pragma unroll
    for (int mt = 0; mt < 4; ++mt) {
        int ro = (mt * 16 + lm) * 64 + quad * 8;
        ah0[mt] = *(const short8*)&lds[1][ro];
        ah1[mt] = *(const short8*)&lds[1][ro + 32];
        al0[mt] = *(const short8*)&lds[1][4096 + ro];
        al1[mt] = *(const short8*)&lds[1][4096 + ro + 32];
        wh0[mt] = *(const short8*)&lds[1][8192 + ro];
        wh1[mt] = *(const short8*)&lds[1][8192 + ro + 32];
        wl0[mt] = *(const short8*)&lds[1][12288 + ro];
        wl1[mt] = *(const short8*)&lds[1][12288 + ro + 32];
    }
    float4 wpv[4];
    float bp0 = 0.f;
    if (FINAL) {
        bp0 = bp[0];
        #pragma unroll
        for (int mt = 0; mt < 4; ++mt) wpv[mt] = *(const float4*)&Wp[mt * 16 + quad * 4];
    }
    __syncthreads();   // lds[1] now free for T2[1]

    #define I2CALL(c, VCUR, VNXT, BCUR, BNXT) \
        i2_chunk<FINAL, c>(VCUR, VNXT, BCUR, BNXT, T2h, T2l, vt, out, \
                           ah0, al0, ah1, al1, wh0, wl0, wh1, wl1, wpv, bp0, \
                           n1, wv, lane, lm, quad)
    I2CALL(0, vA, vB, lds[0], lds[1]);
    I2CALL(1, vB, vA, lds[1], lds[0]);
    I2CALL(2, vA, vB, lds[0], lds[1]);
    I2CALL(3, vB, vA, lds[1], lds[0]);
    I2CALL(4, vA, vB, lds[0], lds[1]);
    I2CALL(5, vB, vA, lds[1], lds[0]);
    I2CALL(6, vA, vB, lds[0], lds[1]);
    I2CALL(7, vB, vA, lds[1], lds[0]);
    #undef I2CALL
}

extern "C" void kernel_launch(void* const* d_in, const int* in_sizes, int n_in,
                              void* d_out, int out_size, void* d_ws, size_t ws_size,
                              hipStream_t stream) {
    const float* in  = (const float*)d_in[0];
    const float* Wsh = (const float*)d_in[1];
    const float* bsh = (const float*)d_in[2];
    const float* Wp  = (const float*)d_in[15];
    const float* bp  = (const float*)d_in[16];

    // workspace layout (~151.9 MB, proven to fit)
    char* wsb = (char*)d_ws;
    ushort_t* vt   = (ushort_t*)wsb;                          // 1024*1024*64 bf16 = 134,217,728 B
    float* ctab = (float*)(wsb + 134217728);                  // 1024
    float* stab = ctab + 1024;                                // 1024
    float* gT   = stab + 1024;                                // 1024*64*64 f32 = 16 MB
    float* Rfr  = gT + 4194304;                               // 65536
    float* Rfi  = Rfr + 65536;                                // 65536
    ushort_t* T1h = (ushort_t*)(Rfi + 65536);                 // 64*1024
    ushort_t* T1l = T1h + 65536;
    ushort_t* T2h = T1l + 65536;                              // 1024*64
    ushort_t* T2l = T2h + 65536;
    ushort_t* wTh = T2l + 65536;                              // 4*64*64
    ushort_t* wTl = wTh + 16384;
    ushort_t* Bh  = (ushort_t*)gT;                            // alias gT (dead after k_f2)
    ushort_t* Bl  = Bh + 4194304;
    float* fpr = (float*)d_out;                               // alias d_out (dead before final k_i2)
    float* fpi = fpr + 524288;

    k_fill_tw<<<4, 256, 0, stream>>>(ctab, stab);
    k_fill_T1<<<256, 256, 0, stream>>>(T1h, T1l);
    k_fill_T2<<<256, 256, 0, stream>>>(T2h, T2l);
    k_fill_wT<<<dim3(16, 4), 256, 0, stream>>>((const float*)d_in[5], (const float*)d_in[8],
                                               (const float*)d_in[11], (const float*)d_in[14], wTh, wTl);
    k_shallow<<<65536, 256, 0, stream>>>(in, Wsh, bsh, vt);
    for (int L = 0; L < 4; ++L) {
        const float* Rr = (const float*)d_in[3 + L * 3];
        const float* Ri = (const float*)d_in[4 + L * 3];
        k_f1<<<1024, 256, 0, stream>>>(vt, T1h, T1l, gT);
        k_f2<<<dim3(8, 16, 4), 256, 0, stream>>>(gT, ctab, stab, fpr, fpi);
        k_mix<<<1024, 64, 0, stream>>>(fpr, fpi, Rr, Ri, Rfr, Rfi);
        k_i1<<<1024, 256, 0, stream>>>(Rfr, Rfi, ctab, stab, Bh, Bl);
        if (L < 3) {
            k_i2<false><<<1024, 256, 0, stream>>>(vt, Bh, Bl, T2h, T2l,
                    wTh + L * 4096, wTl + L * 4096, nullptr, nullptr, nullptr);
        } else {
            k_i2<true><<<1024, 256, 0, stream>>>(vt, Bh, Bl, T2h, T2l,
                    wTh + L * 4096, wTl + L * 4096, Wp, bp, (float*)d_out);
        }
    }
}